// Round 5
// baseline (265.210 us; speedup 1.0000x reference)
//
#include <hip/hip_runtime.h>
#include <hip/hip_fp16.h>

#define N_NODES 50000
#define N_EDGES 800000
#define NBKT 196            // ceil(50000 / 256) coarse buckets (dst >> 8)
#define EPB_BIN 4096        // edges per block in edge-sweep kernels
#define NB_BIN ((N_EDGES + EPB_BIN - 1) / EPB_BIN)   // 196
#define NB_EL 196           // ceil(50000/256) blocks for el9p role
#define NB_PW 48            // 64*192/256 blocks for prepW role

typedef _Float16 half8 __attribute__((ext_vector_type(8)));
typedef float f32x4 __attribute__((ext_vector_type(4)));

static __device__ __forceinline__ float lrelu(float x) { return fmaxf(x, 0.2f * x); }

static __device__ __forceinline__ float2 h2f(float bits) {
    union { float f; __half2 h; } u;
    u.f = bits;
    return __half22float2(u.h);
}
static __device__ __forceinline__ float f2h2(float a, float b) {
    union { float f; __half2 h; } u;
    u.h = __floats2half2_rn(a, b);
    return u.f;
}

// ---------------- fused front kernel: cnt | el9p | prepW | prepA ------------
// cnt role: bucket counts (LDS) + per-node counts (global atomics).
__global__ void __launch_bounds__(256) k_front(const int* __restrict__ dst,
                                               int* __restrict__ bcnt,
                                               int* __restrict__ nodecnt,
                                               const float* __restrict__ x,
                                               const float* __restrict__ W1,
                                               const float* __restrict__ al1,
                                               const float* __restrict__ ar1,
                                               float* __restrict__ xph,
                                               float* __restrict__ er,
                                               const float* __restrict__ W2,
                                               __half* __restrict__ Wt16,
                                               const float* __restrict__ al2,
                                               const float* __restrict__ ar2,
                                               float* __restrict__ Wa2,
                                               float* __restrict__ Wr2) {
    __shared__ int lcnt[NBKT];
    __shared__ float sWa[9 * 3];
    __shared__ float sWr[9 * 3];
    const int t = threadIdx.x;
    const int b = blockIdx.x;

    if (b < NB_BIN) {
        const int e0 = b * EPB_BIN;
        for (int i = t; i < NBKT; i += 256) lcnt[i] = 0;
        __syncthreads();
#pragma unroll
        for (int i = 0; i < 16; ++i) {
            const int e = e0 + i * 256 + t;
            if (e < N_EDGES) {
                const int d = dst[e];
                atomicAdd(&lcnt[d >> 8], 1);
                atomicAdd(&nodecnt[d], 1);
            }
        }
        __syncthreads();
        for (int i = t; i < NBKT; i += 256)
            if (lcnt[i]) atomicAdd(&bcnt[i], lcnt[i]);
        return;
    }
    if (b < NB_BIN + NB_EL) {
        if (t < 27) {
            const int h = t / 9, k = t % 9;
            float sa = 0.f, sr = 0.f;
            for (int f = 0; f < 64; ++f) {
                const float w = W1[k * 192 + h * 64 + f];
                sa += w * al1[h * 64 + f];
                sr += w * ar1[h * 64 + f];
            }
            sWa[k * 3 + h] = sa;
            sWr[k * 3 + h] = sr;
        }
        __syncthreads();
        const int n = (b - NB_BIN) * 256 + t;
        if (n >= N_NODES) return;
        const float* __restrict__ xr = x + (size_t)n * 9;
        float xv[9];
        float a0 = 0.f, a1 = 0.f, a2 = 0.f, r0 = 0.f, r1 = 0.f, r2 = 0.f;
#pragma unroll
        for (int k = 0; k < 9; ++k) {
            xv[k] = xr[k];
            a0 += xv[k] * sWa[k * 3 + 0];
            a1 += xv[k] * sWa[k * 3 + 1];
            a2 += xv[k] * sWa[k * 3 + 2];
            r0 += xv[k] * sWr[k * 3 + 0];
            r1 += xv[k] * sWr[k * 3 + 1];
            r2 += xv[k] * sWr[k * 3 + 2];
        }
        float* __restrict__ xo = xph + (size_t)n * 8;
        *reinterpret_cast<float4*>(xo) = make_float4(a0, a1, a2, f2h2(xv[0], xv[1]));
        *reinterpret_cast<float4*>(xo + 4) =
            make_float4(f2h2(xv[2], xv[3]), f2h2(xv[4], xv[5]),
                        f2h2(xv[6], xv[7]), f2h2(xv[8], 0.f));
        *reinterpret_cast<float4*>(er + (size_t)n * 4) = make_float4(r0, r1, r2, 0.f);
        return;
    }
    if (b < NB_BIN + NB_EL + NB_PW) {
        const int idx = (b - (NB_BIN + NB_EL)) * 256 + t;
        if (idx < 64 * 192) {
            const int n = idx / 192, ke = idx % 192;
            Wt16[idx] = __float2half(W2[(ke & 63) * 192 + (ke >> 6) * 64 + n]);
        }
        return;
    }
    if (t < 192) {
        const int h = t >> 6, k = t & 63;
        float sa = 0.f, sr = 0.f;
        for (int f = 0; f < 64; ++f) {
            const float w = W2[k * 192 + h * 64 + f];
            sa += w * al2[h * 64 + f];
            sr += w * ar2[h * 64 + f];
        }
        Wa2[k * 4 + h] = sa;
        Wr2[k * 4 + h] = sr;
        if (h == 0) { Wa2[k * 4 + 3] = 0.f; Wr2[k * 4 + 3] = 0.f; }
    }
}

// ---------------- rowp build: bucket scan + per-node scan --------------------
__global__ void __launch_bounds__(256) k_build(const int* __restrict__ bcnt,
                                               const int* __restrict__ nodecnt,
                                               int* __restrict__ rowp,
                                               int* __restrict__ fill) {
    __shared__ int sscan[256];
    __shared__ int nscan[256];
    const int t = threadIdx.x;
    const int b = blockIdx.x;
    const int n0 = b << 8;
    // inter-bucket base: inclusive scan of bcnt
    const int bv = (t < NBKT) ? bcnt[t] : 0;
    sscan[t] = bv;
    __syncthreads();
    for (int off = 1; off < 256; off <<= 1) {
        const int u = (t >= off) ? sscan[t - off] : 0;
        __syncthreads();
        sscan[t] += u;
        __syncthreads();
    }
    const int base = (b == 0) ? 0 : sscan[b - 1];
    // intra-bucket: scan of nodecnt
    const int n = n0 + t;
    const int v = (n < N_NODES) ? nodecnt[n] : 0;
    nscan[t] = v;
    __syncthreads();
    for (int off = 1; off < 256; off <<= 1) {
        const int u = (t >= off) ? nscan[t - off] : 0;
        __syncthreads();
        nscan[t] += u;
        __syncthreads();
    }
    if (n < N_NODES) {
        const int r = base + nscan[t] - v;
        rowp[n] = r;
        fill[n] = r;
    }
    if (b == NBKT - 1 && t == 0) rowp[N_NODES] = N_EDGES;
}

// ---------------- edge scatter: direct atomic placement ----------------------
__global__ void __launch_bounds__(256) k_scatter(const int* __restrict__ src,
                                                 const int* __restrict__ dst,
                                                 int* __restrict__ fill,
                                                 int* __restrict__ col) {
    const int t = threadIdx.x;
    const int e0 = blockIdx.x * EPB_BIN;
#pragma unroll
    for (int i = 0; i < 16; ++i) {
        const int e = e0 + i * 256 + t;
        if (e < N_EDGES) {
            const int d = dst[e];
            const int s = src[e];
            const int pos = atomicAdd(&fill[d], 1);
            col[pos] = s;
        }
    }
}

// ---------------- fused L1: agg + gemm2 (2-batch, 32-bit offsets) ------------
__global__ void __launch_bounds__(256, 6) k_l1(const float* __restrict__ xph,
                                               const float* __restrict__ er_in,
                                               const int* __restrict__ rowp,
                                               const int* __restrict__ col,
                                               const float* __restrict__ W1,
                                               const float* __restrict__ b1,
                                               const float* __restrict__ Wa2,
                                               const float* __restrict__ Wr2,
                                               __half* __restrict__ hout,
                                               float* __restrict__ el,
                                               float* __restrict__ er_out) {
    __shared__ union {
        float At[16 * 28];          // agg -> gemm handoff (dead after part compute)
        float vbuf[16][72];         // gemm epilogue staging (aliases At; sync between)
    } u;
    __shared__ float part[3][16][64];
    const int t = threadIdx.x;
    const int wv = t >> 6;
    const int lane = t & 63;
    const int q = lane >> 4;            // node slot within wave
    const int ql = lane & 15;           // lane within quarter
    const int li = wv * 4 + q;          // local node 0..15
    const int nbase = blockIdx.x * 16;  // 3125 * 16 = 50000 exact
    const int n = nbase + li;
    const char* __restrict__ xb = (const char*)xph;

    // ---- aggregation (lane-per-edge, 2-edge batch) ----
    {
        const int jb = rowp[n], je = rowp[n + 1];
        const float4 er4 = *reinterpret_cast<const float4*>(er_in + (size_t)n * 4);
        float acc[27];
#pragma unroll
        for (int j = 0; j < 27; ++j) acc[j] = 0.f;
        float sw0 = 0.f, sw1 = 0.f, sw2 = 0.f;

        for (int e = jb + ql; e < je; e += 32) {
            const int e2 = e + 16;
            const bool v2 = (e2 < je);
            const int off1 = col[e] << 5;
            const int off2 = (v2 ? col[e2] : col[e]) << 5;
            const float4 xa1 = *reinterpret_cast<const float4*>(xb + off1);
            const float4 xb1 = *reinterpret_cast<const float4*>(xb + off1 + 16);
            const float4 xa2 = *reinterpret_cast<const float4*>(xb + off2);
            const float4 xb2 = *reinterpret_cast<const float4*>(xb + off2 + 16);
            const float m2 = v2 ? 1.f : 0.f;
            const float w10 = __expf(lrelu(xa1.x + er4.x));
            const float w11 = __expf(lrelu(xa1.y + er4.y));
            const float w12 = __expf(lrelu(xa1.z + er4.z));
            const float w20 = __expf(lrelu(xa2.x + er4.x)) * m2;
            const float w21 = __expf(lrelu(xa2.y + er4.y)) * m2;
            const float w22 = __expf(lrelu(xa2.z + er4.z)) * m2;
            sw0 += w10 + w20; sw1 += w11 + w21; sw2 += w12 + w22;
            const float2 p10 = h2f(xa1.w), p11 = h2f(xb1.x), p12 = h2f(xb1.y),
                         p13 = h2f(xb1.z), p14 = h2f(xb1.w);
            const float2 p20 = h2f(xa2.w), p21 = h2f(xb2.x), p22 = h2f(xb2.y),
                         p23 = h2f(xb2.z), p24 = h2f(xb2.w);
            const float x1[9] = {p10.x, p10.y, p11.x, p11.y, p12.x, p12.y, p13.x, p13.y, p14.x};
            const float x2[9] = {p20.x, p20.y, p21.x, p21.y, p22.x, p22.y, p23.x, p23.y, p24.x};
#pragma unroll
            for (int k = 0; k < 9; ++k) {
                acc[0 + k]  += w10 * x1[k] + w20 * x2[k];
                acc[9 + k]  += w11 * x1[k] + w21 * x2[k];
                acc[18 + k] += w12 * x1[k] + w22 * x2[k];
            }
        }
#pragma unroll
        for (int off = 1; off < 16; off <<= 1) {
            sw0 += __shfl_xor(sw0, off);
            sw1 += __shfl_xor(sw1, off);
            sw2 += __shfl_xor(sw2, off);
#pragma unroll
            for (int j = 0; j < 27; ++j) acc[j] += __shfl_xor(acc[j], off);
        }
        if (ql == 0) {
            const bool has = (je > jb);
            const float i0 = has ? 1.f / sw0 : 0.f;
            const float i1 = has ? 1.f / sw1 : 0.f;
            const float i2 = has ? 1.f / sw2 : 0.f;
            float* __restrict__ ao = u.At + li * 28;
#pragma unroll
            for (int k = 0; k < 9; ++k) {
                ao[k] = acc[k] * i0;
                ao[9 + k] = acc[9 + k] * i1;
                ao[18 + k] = acc[18 + k] * i2;
            }
        }
    }
    __syncthreads();

    // ---- GEMM (h = wave id, c = lane) ----
    {
        const int h = wv;               // 0..3; h==3 idle for partials
        const int c = lane;
        if (h < 3) {
            float wreg[9];
#pragma unroll
            for (int k = 0; k < 9; ++k) wreg[k] = W1[k * 192 + h * 64 + c];
#pragma unroll
            for (int i = 0; i < 16; ++i) {
                const float* __restrict__ arp = u.At + i * 28 + h * 9;
                float acc = 0.f;
#pragma unroll
                for (int k = 0; k < 9; ++k) acc += arp[k] * wreg[k];
                part[h][i][c] = acc;
            }
        }
        __syncthreads();
        const float bsum = b1[c] + b1[64 + c] + b1[128 + c];
        for (int idx = t; idx < 1024; idx += 256) {
            const int i = idx >> 6, cc = idx & 63;  // cc == c (stride 256)
            const float v = part[0][i][cc] + part[1][i][cc] + part[2][i][cc] + bsum;
            hout[(size_t)(nbase + i) * 64 + cc] = __float2half(v);
            u.vbuf[i][cc] = v;           // aliases At — legal: At dead, sync above
        }
        __syncthreads();
        if (t < 96) {
            const int i = t / 6, r = t % 6;
            const int h3 = (r < 3) ? r : r - 3;
            const float* __restrict__ tab = (r < 3) ? Wa2 : Wr2;
            float s = 0.f;
#pragma unroll 8
            for (int c2 = 0; c2 < 64; ++c2) s += u.vbuf[i][c2] * tab[c2 * 4 + h3];
            if (r < 3) el[(size_t)(nbase + i) * 4 + h3] = s;
            else       er_out[(size_t)(nbase + i) * 4 + h3] = s;
        }
    }
}

// ---------------- L2 aggregation v4: packed LDS float4, 32-bit offsets -------
// Per 2 edges: 1 ds_read_b128 (w0,w1,w2,rowoff) replaces 4 ds_read_b32;
// 32-bit byte offset + uniform base replaces 64-bit per-lane address chain;
// inner loop unrolled x2 so both gathers are in flight together.
__global__ void __launch_bounds__(256, 8) k_aggw64(const __half* __restrict__ x,
                                                   const float* __restrict__ el,
                                                   const float* __restrict__ er,
                                                   const int* __restrict__ rowp,
                                                   const int* __restrict__ col,
                                                   __half* __restrict__ agg) {
    const int wv = threadIdx.x >> 6;
    const int lane = threadIdx.x & 63;
    const int n = blockIdx.x * 4 + wv;          // grid exact
    const int jb = rowp[n], je = rowp[n + 1];

    __shared__ float4 wbuf4[4][64];             // (w0, w1, w2, bitcast(row byte off))
    const float4 er4 = *reinterpret_cast<const float4*>(er + (size_t)n * 4);
    const int p = lane >> 5;
    const int foff = (lane & 31) * 4;           // byte offset of this lane's half2
    const char* __restrict__ xbase = (const char*)x;
    const char* __restrict__ elbase = (const char*)el;
    float a00 = 0.f, a01 = 0.f, a02 = 0.f;
    float a10 = 0.f, a11 = 0.f, a12 = 0.f;
    float sw0 = 0.f, sw1 = 0.f, sw2 = 0.f;

    for (int c0 = jb; c0 < je; c0 += 64) {
        const int cnt = min(64, je - c0);
        if (lane < cnt) {
            const int s = col[c0 + lane];
            const float4 e4 = *reinterpret_cast<const float4*>(elbase + (s << 4));
            const float w0 = __expf(lrelu(e4.x + er4.x));
            const float w1 = __expf(lrelu(e4.y + er4.y));
            const float w2 = __expf(lrelu(e4.z + er4.z));
            wbuf4[wv][lane] = make_float4(w0, w1, w2, __int_as_float(s << 7));
            sw0 += w0; sw1 += w1; sw2 += w2;
        }
        __builtin_amdgcn_wave_barrier();   // LDS written by same wave; no block sync needed
        int e = 0;
        for (; e + 4 <= cnt; e += 4) {
            const float4 q1 = wbuf4[wv][e + p];
            const float4 q2 = wbuf4[wv][e + 2 + p];
            const float2 f1 = __half22float2(*reinterpret_cast<const __half2*>(
                xbase + (__float_as_int(q1.w) + foff)));
            const float2 f2 = __half22float2(*reinterpret_cast<const __half2*>(
                xbase + (__float_as_int(q2.w) + foff)));
            a00 += q1.x * f1.x + q2.x * f2.x;
            a01 += q1.y * f1.x + q2.y * f2.x;
            a02 += q1.z * f1.x + q2.z * f2.x;
            a10 += q1.x * f1.y + q2.x * f2.y;
            a11 += q1.y * f1.y + q2.y * f2.y;
            a12 += q1.z * f1.y + q2.z * f2.y;
        }
        // tail: up to 3 edges
        if (e + p < cnt) {
            const float4 q1 = wbuf4[wv][e + p];
            const float2 f1 = __half22float2(*reinterpret_cast<const __half2*>(
                xbase + (__float_as_int(q1.w) + foff)));
            a00 += q1.x * f1.x; a01 += q1.y * f1.x; a02 += q1.z * f1.x;
            a10 += q1.x * f1.y; a11 += q1.y * f1.y; a12 += q1.z * f1.y;
        }
        if (e + 2 + p < cnt) {
            const float4 q2 = wbuf4[wv][e + 2 + p];
            const float2 f2 = __half22float2(*reinterpret_cast<const __half2*>(
                xbase + (__float_as_int(q2.w) + foff)));
            a00 += q2.x * f2.x; a01 += q2.y * f2.x; a02 += q2.z * f2.x;
            a10 += q2.x * f2.y; a11 += q2.y * f2.y; a12 += q2.z * f2.y;
        }
    }
    a00 += __shfl_xor(a00, 32); a01 += __shfl_xor(a01, 32); a02 += __shfl_xor(a02, 32);
    a10 += __shfl_xor(a10, 32); a11 += __shfl_xor(a11, 32); a12 += __shfl_xor(a12, 32);
#pragma unroll
    for (int off = 32; off > 0; off >>= 1) {
        sw0 += __shfl_xor(sw0, off);
        sw1 += __shfl_xor(sw1, off);
        sw2 += __shfl_xor(sw2, off);
    }
    if (lane < 32) {
        const int f0 = (lane & 31) * 2;
        __half* __restrict__ ao = agg + (size_t)n * 192;
        if (je > jb) {
            const float i0 = 1.f / sw0, i1 = 1.f / sw1, i2 = 1.f / sw2;
            *reinterpret_cast<__half2*>(ao + f0) = __floats2half2_rn(a00 * i0, a10 * i0);
            *reinterpret_cast<__half2*>(ao + 64 + f0) = __floats2half2_rn(a01 * i1, a11 * i1);
            *reinterpret_cast<__half2*>(ao + 128 + f0) = __floats2half2_rn(a02 * i2, a12 * i2);
        } else {
            const __half2 z = __floats2half2_rn(0.f, 0.f);
            *reinterpret_cast<__half2*>(ao + f0) = z;
            *reinterpret_cast<__half2*>(ao + 64 + f0) = z;
            *reinterpret_cast<__half2*>(ao + 128 + f0) = z;
        }
    }
}

// ---------------- fused L2 GEMM (MFMA) + layer-3 features (LDS handoff) ------
__global__ void __launch_bounds__(256) k_l23(const __half* __restrict__ aggH,
                                             const __half* __restrict__ Wt,
                                             const float* __restrict__ b2,
                                             const float* __restrict__ W3,
                                             const float* __restrict__ al3,
                                             const float* __restrict__ ar3,
                                             float* __restrict__ feat3p,
                                             float* __restrict__ er3) {
    __shared__ float xl[64 * 68];
    __shared__ float Wl[64 * 6];
    __shared__ float Wal[64 * 3];
    __shared__ float Wrl[64 * 3];
    const int t = threadIdx.x;
    const int n0 = blockIdx.x * 64;             // 782 blocks; last has nvalid=16
    const int nvalid = min(64, N_NODES - n0);

    {
        const int wv = t >> 6;
        const int lane = t & 63;
        const int quad = lane >> 4;
        const int t16 = lane & 15;
        const int nwave = n0 + wv * 16;
        const int arow = min(nwave + t16, N_NODES - 1);
        half8 a[6];
#pragma unroll
        for (int kb = 0; kb < 6; ++kb)
            a[kb] = *reinterpret_cast<const half8*>(aggH + (size_t)arow * 192 + kb * 32 + quad * 8);
#pragma unroll
        for (int nt = 0; nt < 4; ++nt) {
            const int c = nt * 16 + t16;
            const float bs = b2[c] + b2[64 + c] + b2[128 + c];
            const __half* __restrict__ bt = Wt + (size_t)c * 192 + quad * 8;
            f32x4 acc = {0.f, 0.f, 0.f, 0.f};
#pragma unroll
            for (int kb = 0; kb < 6; ++kb) {
                const half8 bfr = *reinterpret_cast<const half8*>(bt + kb * 32);
                acc = __builtin_amdgcn_mfma_f32_16x16x32_f16(a[kb], bfr, acc, 0, 0, 0);
            }
#pragma unroll
            for (int r = 0; r < 4; ++r)
                xl[(wv * 16 + quad * 4 + r) * 68 + c] = acc[r] + bs;
        }
    }
    for (int idx = t; idx < 384; idx += 256) Wl[idx] = W3[idx];
    if (t < 192) {
        const int k = t & 63, h = t >> 6;
        Wal[k * 3 + h] = W3[k * 6 + h * 2] * al3[h * 2] + W3[k * 6 + h * 2 + 1] * al3[h * 2 + 1];
        Wrl[k * 3 + h] = W3[k * 6 + h * 2] * ar3[h * 2] + W3[k * 6 + h * 2 + 1] * ar3[h * 2 + 1];
    }
    __syncthreads();

#pragma unroll
    for (int hp = 0; hp < 2; ++hp) {
        const int i = (t >> 3) + hp * 32;
        const int slot = t & 7;
        if (i < nvalid && slot < 6) {
            float acc = 0.f;
#pragma unroll
            for (int k4 = 0; k4 < 16; ++k4) {
                const float4 xv = *reinterpret_cast<const float4*>(&xl[i * 68 + 4 * k4]);
                acc += Wl[(4 * k4 + 0) * 6 + slot] * xv.x;
                acc += Wl[(4 * k4 + 1) * 6 + slot] * xv.y;
                acc += Wl[(4 * k4 + 2) * 6 + slot] * xv.z;
                acc += Wl[(4 * k4 + 3) * 6 + slot] * xv.w;
            }
            reinterpret_cast<__half*>(feat3p + (size_t)(n0 + i) * 8)[6 + slot] = __float2half(acc);
        }
        if (t < 192) {
            const int ii = t / 6 + hp * 32, ss = t % 6;
            if (ii < nvalid) {
                const int hh = (ss < 3) ? ss : ss - 3;
                const float* __restrict__ wt = (ss < 3) ? Wal : Wrl;
                float acc = 0.f;
#pragma unroll 4
                for (int k = 0; k < 64; ++k) acc += xl[ii * 68 + k] * wt[k * 3 + hh];
                if (ss < 3) feat3p[(size_t)(n0 + ii) * 8 + hh] = acc;   // el3 f32 at 0..2
                else        er3[(size_t)(n0 + ii) * 4 + hh] = acc;
            }
        }
    }
}

// ---------------- layer-3 aggregation: 4-edge batch, 32-bit offsets ----------
__global__ void __launch_bounds__(256, 4) k_agg3(const float* __restrict__ feat3p,
                                                 const float* __restrict__ er3,
                                                 const float* __restrict__ b3,
                                                 const int* __restrict__ rowp,
                                                 const int* __restrict__ col,
                                                 float* __restrict__ out) {
    const int tid = threadIdx.x;
    const int wv = tid >> 6;
    const int lane = tid & 63;
    const int q = lane >> 4;
    const int ql = lane & 15;
    const int n = (blockIdx.x * 4 + wv) * 4 + q;   // grid exact: 3125*16 = 50000
    const int jb = rowp[n], je = rowp[n + 1];
    const float4 er4 = *reinterpret_cast<const float4*>(er3 + (size_t)n * 4);
    const char* __restrict__ fb = (const char*)feat3p;

    float acc[6];
#pragma unroll
    for (int j = 0; j < 6; ++j) acc[j] = 0.f;
    float sw0 = 0.f, sw1 = 0.f, sw2 = 0.f;

    for (int e = jb + ql; e < je; e += 64) {
        const int eb = e + 16, ec = e + 32, ed = e + 48;
        const bool vb = (eb < je), vc = (ec < je), vd = (ed < je);
        const int sa = col[e];
        const int offa = sa << 5;
        const int offb = (vb ? col[eb] : sa) << 5;
        const int offc = (vc ? col[ec] : sa) << 5;
        const int offd = (vd ? col[ed] : sa) << 5;
        const float4 fa1 = *reinterpret_cast<const float4*>(fb + offa);
        const float2 fb1 = *reinterpret_cast<const float2*>(fb + offa + 16);
        const float4 fa2 = *reinterpret_cast<const float4*>(fb + offb);
        const float2 fb2 = *reinterpret_cast<const float2*>(fb + offb + 16);
        const float4 fa3 = *reinterpret_cast<const float4*>(fb + offc);
        const float2 fb3 = *reinterpret_cast<const float2*>(fb + offc + 16);
        const float4 fa4 = *reinterpret_cast<const float4*>(fb + offd);
        const float2 fb4 = *reinterpret_cast<const float2*>(fb + offd + 16);
        const float mb = vb ? 1.f : 0.f, mc = vc ? 1.f : 0.f, md = vd ? 1.f : 0.f;
        const float w10 = __expf(lrelu(fa1.x + er4.x));
        const float w11 = __expf(lrelu(fa1.y + er4.y));
        const float w12 = __expf(lrelu(fa1.z + er4.z));
        const float w20 = __expf(lrelu(fa2.x + er4.x)) * mb;
        const float w21 = __expf(lrelu(fa2.y + er4.y)) * mb;
        const float w22 = __expf(lrelu(fa2.z + er4.z)) * mb;
        const float w30 = __expf(lrelu(fa3.x + er4.x)) * mc;
        const float w31 = __expf(lrelu(fa3.y + er4.y)) * mc;
        const float w32 = __expf(lrelu(fa3.z + er4.z)) * mc;
        const float w40 = __expf(lrelu(fa4.x + er4.x)) * md;
        const float w41 = __expf(lrelu(fa4.y + er4.y)) * md;
        const float w42 = __expf(lrelu(fa4.z + er4.z)) * md;
        sw0 += (w10 + w20) + (w30 + w40);
        sw1 += (w11 + w21) + (w31 + w41);
        sw2 += (w12 + w22) + (w32 + w42);
        const float2 f01a = h2f(fa1.w), f23a = h2f(fb1.x), f45a = h2f(fb1.y);
        const float2 f01b = h2f(fa2.w), f23b = h2f(fb2.x), f45b = h2f(fb2.y);
        const float2 f01c = h2f(fa3.w), f23c = h2f(fb3.x), f45c = h2f(fb3.y);
        const float2 f01d = h2f(fa4.w), f23d = h2f(fb4.x), f45d = h2f(fb4.y);
        acc[0] += (w10 * f01a.x + w20 * f01b.x) + (w30 * f01c.x + w40 * f01d.x);
        acc[1] += (w10 * f01a.y + w20 * f01b.y) + (w30 * f01c.y + w40 * f01d.y);
        acc[2] += (w11 * f23a.x + w21 * f23b.x) + (w31 * f23c.x + w41 * f23d.x);
        acc[3] += (w11 * f23a.y + w21 * f23b.y) + (w31 * f23c.y + w41 * f23d.y);
        acc[4] += (w12 * f45a.x + w22 * f45b.x) + (w32 * f45c.x + w42 * f45d.x);
        acc[5] += (w12 * f45a.y + w22 * f45b.y) + (w32 * f45c.y + w42 * f45d.y);
    }
#pragma unroll
    for (int off = 1; off < 16; off <<= 1) {
        sw0 += __shfl_xor(sw0, off);
        sw1 += __shfl_xor(sw1, off);
        sw2 += __shfl_xor(sw2, off);
#pragma unroll
        for (int j = 0; j < 6; ++j) acc[j] += __shfl_xor(acc[j], off);
    }
    if (ql == 0) {
        const bool has = (je > jb);
        const float i0 = has ? 1.f / sw0 : 0.f;
        const float i1 = has ? 1.f / sw1 : 0.f;
        const float i2 = has ? 1.f / sw2 : 0.f;
        const float o0 = acc[0] * i0 + acc[2] * i1 + acc[4] * i2 + b3[0] + b3[2] + b3[4];
        const float o1 = acc[1] * i0 + acc[3] * i1 + acc[5] * i2 + b3[1] + b3[3] + b3[5];
        *reinterpret_cast<float2*>(out + (size_t)n * 2) = make_float2(o0, o1);
    }
}

extern "C" void kernel_launch(void* const* d_in, const int* in_sizes, int n_in,
                              void* d_out, int out_size, void* d_ws, size_t ws_size,
                              hipStream_t stream) {
    const float* feats = (const float*)d_in[0];
    const int* src = (const int*)d_in[1];
    const int* dst = (const int*)d_in[2];
    const float* W1 = (const float*)d_in[3];
    const float* al1 = (const float*)d_in[4];
    const float* ar1 = (const float*)d_in[5];
    const float* b1 = (const float*)d_in[6];
    const float* W2 = (const float*)d_in[7];
    const float* al2 = (const float*)d_in[8];
    const float* ar2 = (const float*)d_in[9];
    const float* b2 = (const float*)d_in[10];
    const float* W3 = (const float*)d_in[11];
    const float* al3 = (const float*)d_in[12];
    const float* ar3 = (const float*)d_in[13];
    const float* b3 = (const float*)d_in[14];
    float* out = (float*)d_out;

    char* ws = (char*)d_ws;
    size_t off = 0;
    auto alloc = [&](size_t bytes) {
        void* p = ws + off;
        off += (bytes + 255) & ~(size_t)255;
        return p;
    };
    __half* aggH = (__half*)alloc((size_t)N_NODES * 192 * 2);    // L2 agg fp16 [N][192]
    __half* hbufH = (__half*)alloc((size_t)N_NODES * 64 * 2);    // fp16 L1 hidden
    float* xph = (float*)alloc((size_t)N_NODES * 8 * 4);         // packed el1(f32)+x(f16)
    float* el = (float*)alloc((size_t)N_NODES * 4 * 4);
    float* er = (float*)alloc((size_t)N_NODES * 4 * 4);
    int* cnts = (int*)alloc((size_t)(256 + N_NODES) * 4);        // bcnt[256] + nodecnt[50000]
    int* bcnt = cnts;
    int* nodecnt = cnts + 256;
    int* fill = (int*)alloc((size_t)N_NODES * 4);
    int* rowp = (int*)alloc((size_t)(N_NODES + 1) * 4);
    int* col = (int*)alloc((size_t)N_EDGES * 4);
    __half* Wt16 = (__half*)alloc((size_t)64 * 192 * 2);         // 24 KB fp16 W2^T
    float* Wa2 = (float*)alloc(256 * 4);
    float* Wr2 = (float*)alloc(256 * 4);
    float* feat3p = (float*)alloc((size_t)N_NODES * 8 * 4);      // packed el3(f32)+feat(f16)
    (void)ws_size;

    const int ab = N_NODES / 4;             // k_aggw64: 4 waves/block
    const int qb = N_NODES / 16;            // 16 nodes/block kernels
    const int lb = (N_NODES + 63) / 64;     // k_l23: 64 nodes/block

    // ---- CSR build + front prep ----
    hipMemsetAsync(cnts, 0, (size_t)(256 + N_NODES) * 4, stream);
    k_front<<<NB_BIN + NB_EL + NB_PW + 1, 256, 0, stream>>>(
        dst, bcnt, nodecnt, feats, W1, al1, ar1, xph, er, W2, Wt16, al2, ar2, Wa2, Wr2);
    k_build<<<NBKT, 256, 0, stream>>>(bcnt, nodecnt, rowp, fill);
    k_scatter<<<NB_BIN, 256, 0, stream>>>(src, dst, fill, col);

    // ---- layer 1 (agg + GEMM fused) ----
    k_l1<<<qb, 256, 0, stream>>>(xph, er, rowp, col, W1, b1, Wa2, Wr2, hbufH, el, er);

    // ---- layer 2 aggregation ----
    k_aggw64<<<ab, 256, 0, stream>>>(hbufH, el, er, rowp, col, aggH);

    // ---- layer-2 GEMM + layer-3 features (fused) ----
    k_l23<<<lb, 256, 0, stream>>>(aggH, Wt16, b2, W3, al3, ar3, feat3p, er);

    // ---- layer 3 aggregation ----
    k_agg3<<<qb, 256, 0, stream>>>(feat3p, er, b3, rowp, col, out);
}

// Round 6
// 219.303 us; speedup vs baseline: 1.2093x; 1.2093x over previous
//
#include <hip/hip_runtime.h>
#include <hip/hip_fp16.h>

#define N_NODES 50000
#define N_EDGES 800000
#define NBKT 196            // ceil(50000 / 256) coarse buckets (dst >> 8)
#define EPB_BIN 4096        // edges per binning block
#define NB_BIN ((N_EDGES + EPB_BIN - 1) / EPB_BIN)   // 196
#define NB_EL 196           // ceil(50000/256) blocks for el9p role
#define NB_PW 48            // 64*192/256 blocks for prepW role

typedef _Float16 half8 __attribute__((ext_vector_type(8)));
typedef float f32x4 __attribute__((ext_vector_type(4)));

static __device__ __forceinline__ float lrelu(float x) { return fmaxf(x, 0.2f * x); }

static __device__ __forceinline__ float2 h2f(float bits) {
    union { float f; __half2 h; } u;
    u.f = bits;
    return __half22float2(u.h);
}
static __device__ __forceinline__ float f2h2(float a, float b) {
    union { float f; __half2 h; } u;
    u.h = __floats2half2_rn(a, b);
    return u.f;
}

// ---------------- fused front kernel: cntb | el9p | prepW | prepA -----------
// (round-4 version: bucket counts only, NO per-node atomics)
__global__ void __launch_bounds__(256) k_front(const int* __restrict__ dst,
                                               int* __restrict__ bcnt,
                                               const float* __restrict__ x,
                                               const float* __restrict__ W1,
                                               const float* __restrict__ al1,
                                               const float* __restrict__ ar1,
                                               float* __restrict__ xph,
                                               float* __restrict__ er,
                                               const float* __restrict__ W2,
                                               __half* __restrict__ Wt16,
                                               const float* __restrict__ al2,
                                               const float* __restrict__ ar2,
                                               float* __restrict__ Wa2,
                                               float* __restrict__ Wr2) {
    __shared__ int lcnt[NBKT];
    __shared__ float sWa[9 * 3];
    __shared__ float sWr[9 * 3];
    const int t = threadIdx.x;
    const int b = blockIdx.x;

    if (b < NB_BIN) {
        const int e0 = b * EPB_BIN;
        for (int i = t; i < NBKT; i += 256) lcnt[i] = 0;
        __syncthreads();
#pragma unroll
        for (int i = 0; i < 16; ++i) {
            const int e = e0 + i * 256 + t;
            if (e < N_EDGES) atomicAdd(&lcnt[dst[e] >> 8], 1);
        }
        __syncthreads();
        for (int i = t; i < NBKT; i += 256)
            if (lcnt[i]) atomicAdd(&bcnt[i], lcnt[i]);
        return;
    }
    if (b < NB_BIN + NB_EL) {
        if (t < 27) {
            const int h = t / 9, k = t % 9;
            float sa = 0.f, sr = 0.f;
            for (int f = 0; f < 64; ++f) {
                const float w = W1[k * 192 + h * 64 + f];
                sa += w * al1[h * 64 + f];
                sr += w * ar1[h * 64 + f];
            }
            sWa[k * 3 + h] = sa;
            sWr[k * 3 + h] = sr;
        }
        __syncthreads();
        const int n = (b - NB_BIN) * 256 + t;
        if (n >= N_NODES) return;
        const float* __restrict__ xr = x + (size_t)n * 9;
        float xv[9];
        float a0 = 0.f, a1 = 0.f, a2 = 0.f, r0 = 0.f, r1 = 0.f, r2 = 0.f;
#pragma unroll
        for (int k = 0; k < 9; ++k) {
            xv[k] = xr[k];
            a0 += xv[k] * sWa[k * 3 + 0];
            a1 += xv[k] * sWa[k * 3 + 1];
            a2 += xv[k] * sWa[k * 3 + 2];
            r0 += xv[k] * sWr[k * 3 + 0];
            r1 += xv[k] * sWr[k * 3 + 1];
            r2 += xv[k] * sWr[k * 3 + 2];
        }
        float* __restrict__ xo = xph + (size_t)n * 8;
        *reinterpret_cast<float4*>(xo) = make_float4(a0, a1, a2, f2h2(xv[0], xv[1]));
        *reinterpret_cast<float4*>(xo + 4) =
            make_float4(f2h2(xv[2], xv[3]), f2h2(xv[4], xv[5]),
                        f2h2(xv[6], xv[7]), f2h2(xv[8], 0.f));
        *reinterpret_cast<float4*>(er + (size_t)n * 4) = make_float4(r0, r1, r2, 0.f);
        return;
    }
    if (b < NB_BIN + NB_EL + NB_PW) {
        const int idx = (b - (NB_BIN + NB_EL)) * 256 + t;
        if (idx < 64 * 192) {
            const int n = idx / 192, ke = idx % 192;
            Wt16[idx] = __float2half(W2[(ke & 63) * 192 + (ke >> 6) * 64 + n]);
        }
        return;
    }
    if (t < 192) {
        const int h = t >> 6, k = t & 63;
        float sa = 0.f, sr = 0.f;
        for (int f = 0; f < 64; ++f) {
            const float w = W2[k * 192 + h * 64 + f];
            sa += w * al2[h * 64 + f];
            sr += w * ar2[h * 64 + f];
        }
        Wa2[k * 4 + h] = sa;
        Wr2[k * 4 + h] = sr;
        if (h == 0) { Wa2[k * 4 + 3] = 0.f; Wr2[k * 4 + 3] = 0.f; }
    }
}

// ---------------- bin edges (bucket scan inlined) ----------------------------
// Bucket-staged writes: scatter locality within 256-node buckets avoids the
// 16x line write-amplification measured on direct random scatter (round 5).
__global__ void __launch_bounds__(256) k_bin(const int* __restrict__ src,
                                             const int* __restrict__ dst,
                                             const int* __restrict__ bcnt,
                                             int* __restrict__ bfill,
                                             unsigned int* __restrict__ stage) {
    __shared__ int lcnt[NBKT];
    __shared__ int gb[NBKT];
    __shared__ int lf[NBKT];
    __shared__ int sscan[256];
    __shared__ int sbase[256];
    const int t = threadIdx.x;
    const int e0 = blockIdx.x * EPB_BIN;
    const int bv = (t < NBKT) ? bcnt[t] : 0;
    sscan[t] = bv;
    if (t < NBKT) lcnt[t] = 0;
    __syncthreads();
    for (int off = 1; off < 256; off <<= 1) {
        const int u = (t >= off) ? sscan[t - off] : 0;
        __syncthreads();
        sscan[t] += u;
        __syncthreads();
    }
    sbase[t] = sscan[t] - bv;
    int dcache[16];
#pragma unroll
    for (int i = 0; i < 16; ++i) {
        const int e = e0 + i * 256 + t;
        if (e < N_EDGES) {
            const int d = dst[e];
            dcache[i] = d;
            atomicAdd(&lcnt[d >> 8], 1);
        } else dcache[i] = -1;
    }
    __syncthreads();
    for (int i = t; i < NBKT; i += 256) {
        gb[i] = sbase[i] + atomicAdd(&bfill[i], lcnt[i]);
        lf[i] = 0;
    }
    __syncthreads();
#pragma unroll
    for (int i = 0; i < 16; ++i) {
        const int e = e0 + i * 256 + t;
        if (e < N_EDGES) {
            const int d = dcache[i];
            const int bk = d >> 8;
            const int r = atomicAdd(&lf[bk], 1);
            stage[gb[bk] + r] = (unsigned int)src[e] | ((unsigned int)(d & 255) << 16);
        }
    }
}

// ---------------- per bucket scatter (bucket scan inlined) ------------------
__global__ void __launch_bounds__(256) k_bscatter2(const unsigned int* __restrict__ stage,
                                                   const int* __restrict__ bcnt,
                                                   int* __restrict__ rowp,
                                                   int* __restrict__ col) {
    __shared__ int lcnt[256];
    __shared__ int lpos[256];
    __shared__ int sexc[256];
    __shared__ int sscan[256];
    const int t = threadIdx.x;
    const int b = blockIdx.x;
    const int n0 = b << 8;
    const int bv = (t < NBKT) ? bcnt[t] : 0;
    sscan[t] = bv;
    lcnt[t] = 0;
    __syncthreads();
    for (int off = 1; off < 256; off <<= 1) {
        const int u = (t >= off) ? sscan[t - off] : 0;
        __syncthreads();
        sscan[t] += u;
        __syncthreads();
    }
    const int base = (b == 0) ? 0 : sscan[b - 1];
    const int end = sscan[b];

    for (int j = base + t; j < end; j += 256)
        atomicAdd(&lcnt[(stage[j] >> 16) & 255], 1);
    __syncthreads();
    const int v = lcnt[t];
    lpos[t] = v;
    __syncthreads();
    for (int off = 1; off < 256; off <<= 1) {
        const int u = (t >= off) ? lpos[t - off] : 0;
        __syncthreads();
        lpos[t] += u;
        __syncthreads();
    }
    sexc[t] = lpos[t] - v;
    if (n0 + t < N_NODES) rowp[n0 + t] = base + sexc[t];
    if (b == NBKT - 1 && t == 0) rowp[N_NODES] = N_EDGES;
    lcnt[t] = 0;   // reuse as fill counters
    __syncthreads();
    for (int j = base + t; j < end; j += 256) {
        const unsigned int e = stage[j];
        const int local = (int)(e >> 16) & 255;
        const int r = atomicAdd(&lcnt[local], 1);
        col[base + sexc[local] + r] = (int)(e & 0xFFFFu);
    }
}

// ---------------- fused L1: agg + gemm2 (2-batch, 32-bit offsets) ------------
__global__ void __launch_bounds__(256, 6) k_l1(const float* __restrict__ xph,
                                               const float* __restrict__ er_in,
                                               const int* __restrict__ rowp,
                                               const int* __restrict__ col,
                                               const float* __restrict__ W1,
                                               const float* __restrict__ b1,
                                               const float* __restrict__ Wa2,
                                               const float* __restrict__ Wr2,
                                               __half* __restrict__ hout,
                                               float* __restrict__ el,
                                               float* __restrict__ er_out) {
    __shared__ union {
        float At[16 * 28];          // agg -> gemm handoff (dead after part compute)
        float vbuf[16][72];         // gemm epilogue staging (aliases At; sync between)
    } u;
    __shared__ float part[3][16][64];
    const int t = threadIdx.x;
    const int wv = t >> 6;
    const int lane = t & 63;
    const int q = lane >> 4;            // node slot within wave
    const int ql = lane & 15;           // lane within quarter
    const int li = wv * 4 + q;          // local node 0..15
    const int nbase = blockIdx.x * 16;  // 3125 * 16 = 50000 exact
    const int n = nbase + li;
    const char* __restrict__ xb = (const char*)xph;

    // ---- aggregation (lane-per-edge, 2-edge batch) ----
    {
        const int jb = rowp[n], je = rowp[n + 1];
        const float4 er4 = *reinterpret_cast<const float4*>(er_in + (size_t)n * 4);
        float acc[27];
#pragma unroll
        for (int j = 0; j < 27; ++j) acc[j] = 0.f;
        float sw0 = 0.f, sw1 = 0.f, sw2 = 0.f;

        for (int e = jb + ql; e < je; e += 32) {
            const int e2 = e + 16;
            const bool v2 = (e2 < je);
            const int off1 = col[e] << 5;
            const int off2 = (v2 ? col[e2] : col[e]) << 5;
            const float4 xa1 = *reinterpret_cast<const float4*>(xb + off1);
            const float4 xb1 = *reinterpret_cast<const float4*>(xb + off1 + 16);
            const float4 xa2 = *reinterpret_cast<const float4*>(xb + off2);
            const float4 xb2 = *reinterpret_cast<const float4*>(xb + off2 + 16);
            const float m2 = v2 ? 1.f : 0.f;
            const float w10 = __expf(lrelu(xa1.x + er4.x));
            const float w11 = __expf(lrelu(xa1.y + er4.y));
            const float w12 = __expf(lrelu(xa1.z + er4.z));
            const float w20 = __expf(lrelu(xa2.x + er4.x)) * m2;
            const float w21 = __expf(lrelu(xa2.y + er4.y)) * m2;
            const float w22 = __expf(lrelu(xa2.z + er4.z)) * m2;
            sw0 += w10 + w20; sw1 += w11 + w21; sw2 += w12 + w22;
            const float2 p10 = h2f(xa1.w), p11 = h2f(xb1.x), p12 = h2f(xb1.y),
                         p13 = h2f(xb1.z), p14 = h2f(xb1.w);
            const float2 p20 = h2f(xa2.w), p21 = h2f(xb2.x), p22 = h2f(xb2.y),
                         p23 = h2f(xb2.z), p24 = h2f(xb2.w);
            const float x1[9] = {p10.x, p10.y, p11.x, p11.y, p12.x, p12.y, p13.x, p13.y, p14.x};
            const float x2[9] = {p20.x, p20.y, p21.x, p21.y, p22.x, p22.y, p23.x, p23.y, p24.x};
#pragma unroll
            for (int k = 0; k < 9; ++k) {
                acc[0 + k]  += w10 * x1[k] + w20 * x2[k];
                acc[9 + k]  += w11 * x1[k] + w21 * x2[k];
                acc[18 + k] += w12 * x1[k] + w22 * x2[k];
            }
        }
#pragma unroll
        for (int off = 1; off < 16; off <<= 1) {
            sw0 += __shfl_xor(sw0, off);
            sw1 += __shfl_xor(sw1, off);
            sw2 += __shfl_xor(sw2, off);
#pragma unroll
            for (int j = 0; j < 27; ++j) acc[j] += __shfl_xor(acc[j], off);
        }
        if (ql == 0) {
            const bool has = (je > jb);
            const float i0 = has ? 1.f / sw0 : 0.f;
            const float i1 = has ? 1.f / sw1 : 0.f;
            const float i2 = has ? 1.f / sw2 : 0.f;
            float* __restrict__ ao = u.At + li * 28;
#pragma unroll
            for (int k = 0; k < 9; ++k) {
                ao[k] = acc[k] * i0;
                ao[9 + k] = acc[9 + k] * i1;
                ao[18 + k] = acc[18 + k] * i2;
            }
        }
    }
    __syncthreads();

    // ---- GEMM (h = wave id, c = lane) ----
    {
        const int h = wv;               // 0..3; h==3 idle for partials
        const int c = lane;
        if (h < 3) {
            float wreg[9];
#pragma unroll
            for (int k = 0; k < 9; ++k) wreg[k] = W1[k * 192 + h * 64 + c];
#pragma unroll
            for (int i = 0; i < 16; ++i) {
                const float* __restrict__ arp = u.At + i * 28 + h * 9;
                float acc = 0.f;
#pragma unroll
                for (int k = 0; k < 9; ++k) acc += arp[k] * wreg[k];
                part[h][i][c] = acc;
            }
        }
        __syncthreads();
        const float bsum = b1[c] + b1[64 + c] + b1[128 + c];
        for (int idx = t; idx < 1024; idx += 256) {
            const int i = idx >> 6, cc = idx & 63;  // cc == c (stride 256)
            const float v = part[0][i][cc] + part[1][i][cc] + part[2][i][cc] + bsum;
            hout[(size_t)(nbase + i) * 64 + cc] = __float2half(v);
            u.vbuf[i][cc] = v;           // aliases At — legal: At dead, sync above
        }
        __syncthreads();
        if (t < 96) {
            const int i = t / 6, r = t % 6;
            const int h3 = (r < 3) ? r : r - 3;
            const float* __restrict__ tab = (r < 3) ? Wa2 : Wr2;
            float s = 0.f;
#pragma unroll 8
            for (int c2 = 0; c2 < 64; ++c2) s += u.vbuf[i][c2] * tab[c2 * 4 + h3];
            if (r < 3) el[(size_t)(nbase + i) * 4 + h3] = s;
            else       er_out[(size_t)(nbase + i) * 4 + h3] = s;
        }
    }
}

// ---------------- L2 aggregation v4: packed LDS float4, 32-bit offsets -------
__global__ void __launch_bounds__(256, 8) k_aggw64(const __half* __restrict__ x,
                                                   const float* __restrict__ el,
                                                   const float* __restrict__ er,
                                                   const int* __restrict__ rowp,
                                                   const int* __restrict__ col,
                                                   __half* __restrict__ agg) {
    const int wv = threadIdx.x >> 6;
    const int lane = threadIdx.x & 63;
    const int n = blockIdx.x * 4 + wv;          // grid exact
    const int jb = rowp[n], je = rowp[n + 1];

    __shared__ float4 wbuf4[4][64];             // (w0, w1, w2, bitcast(row byte off))
    const float4 er4 = *reinterpret_cast<const float4*>(er + (size_t)n * 4);
    const int p = lane >> 5;
    const int foff = (lane & 31) * 4;           // byte offset of this lane's half2
    const char* __restrict__ xbase = (const char*)x;
    const char* __restrict__ elbase = (const char*)el;
    float a00 = 0.f, a01 = 0.f, a02 = 0.f;
    float a10 = 0.f, a11 = 0.f, a12 = 0.f;
    float sw0 = 0.f, sw1 = 0.f, sw2 = 0.f;

    for (int c0 = jb; c0 < je; c0 += 64) {
        const int cnt = min(64, je - c0);
        if (lane < cnt) {
            const int s = col[c0 + lane];
            const float4 e4 = *reinterpret_cast<const float4*>(elbase + (s << 4));
            const float w0 = __expf(lrelu(e4.x + er4.x));
            const float w1 = __expf(lrelu(e4.y + er4.y));
            const float w2 = __expf(lrelu(e4.z + er4.z));
            wbuf4[wv][lane] = make_float4(w0, w1, w2, __int_as_float(s << 7));
            sw0 += w0; sw1 += w1; sw2 += w2;
        }
        __builtin_amdgcn_wave_barrier();   // LDS written by same wave; no block sync needed
        int e = 0;
        for (; e + 4 <= cnt; e += 4) {
            const float4 q1 = wbuf4[wv][e + p];
            const float4 q2 = wbuf4[wv][e + 2 + p];
            const float2 f1 = __half22float2(*reinterpret_cast<const __half2*>(
                xbase + (__float_as_int(q1.w) + foff)));
            const float2 f2 = __half22float2(*reinterpret_cast<const __half2*>(
                xbase + (__float_as_int(q2.w) + foff)));
            a00 += q1.x * f1.x + q2.x * f2.x;
            a01 += q1.y * f1.x + q2.y * f2.x;
            a02 += q1.z * f1.x + q2.z * f2.x;
            a10 += q1.x * f1.y + q2.x * f2.y;
            a11 += q1.y * f1.y + q2.y * f2.y;
            a12 += q1.z * f1.y + q2.z * f2.y;
        }
        if (e + p < cnt) {
            const float4 q1 = wbuf4[wv][e + p];
            const float2 f1 = __half22float2(*reinterpret_cast<const __half2*>(
                xbase + (__float_as_int(q1.w) + foff)));
            a00 += q1.x * f1.x; a01 += q1.y * f1.x; a02 += q1.z * f1.x;
            a10 += q1.x * f1.y; a11 += q1.y * f1.y; a12 += q1.z * f1.y;
        }
        if (e + 2 + p < cnt) {
            const float4 q2 = wbuf4[wv][e + 2 + p];
            const float2 f2 = __half22float2(*reinterpret_cast<const __half2*>(
                xbase + (__float_as_int(q2.w) + foff)));
            a00 += q2.x * f2.x; a01 += q2.y * f2.x; a02 += q2.z * f2.x;
            a10 += q2.x * f2.y; a11 += q2.y * f2.y; a12 += q2.z * f2.y;
        }
    }
    a00 += __shfl_xor(a00, 32); a01 += __shfl_xor(a01, 32); a02 += __shfl_xor(a02, 32);
    a10 += __shfl_xor(a10, 32); a11 += __shfl_xor(a11, 32); a12 += __shfl_xor(a12, 32);
#pragma unroll
    for (int off = 32; off > 0; off >>= 1) {
        sw0 += __shfl_xor(sw0, off);
        sw1 += __shfl_xor(sw1, off);
        sw2 += __shfl_xor(sw2, off);
    }
    if (lane < 32) {
        const int f0 = (lane & 31) * 2;
        __half* __restrict__ ao = agg + (size_t)n * 192;
        if (je > jb) {
            const float i0 = 1.f / sw0, i1 = 1.f / sw1, i2 = 1.f / sw2;
            *reinterpret_cast<__half2*>(ao + f0) = __floats2half2_rn(a00 * i0, a10 * i0);
            *reinterpret_cast<__half2*>(ao + 64 + f0) = __floats2half2_rn(a01 * i1, a11 * i1);
            *reinterpret_cast<__half2*>(ao + 128 + f0) = __floats2half2_rn(a02 * i2, a12 * i2);
        } else {
            const __half2 z = __floats2half2_rn(0.f, 0.f);
            *reinterpret_cast<__half2*>(ao + f0) = z;
            *reinterpret_cast<__half2*>(ao + 64 + f0) = z;
            *reinterpret_cast<__half2*>(ao + 128 + f0) = z;
        }
    }
}

// ---------------- fused L2 GEMM (MFMA) + layer-3 features (LDS handoff) ------
__global__ void __launch_bounds__(256) k_l23(const __half* __restrict__ aggH,
                                             const __half* __restrict__ Wt,
                                             const float* __restrict__ b2,
                                             const float* __restrict__ W3,
                                             const float* __restrict__ al3,
                                             const float* __restrict__ ar3,
                                             float* __restrict__ feat3p,
                                             float* __restrict__ er3) {
    __shared__ float xl[64 * 68];
    __shared__ float Wl[64 * 6];
    __shared__ float Wal[64 * 3];
    __shared__ float Wrl[64 * 3];
    const int t = threadIdx.x;
    const int n0 = blockIdx.x * 64;             // 782 blocks; last has nvalid=16
    const int nvalid = min(64, N_NODES - n0);

    {
        const int wv = t >> 6;
        const int lane = t & 63;
        const int quad = lane >> 4;
        const int t16 = lane & 15;
        const int nwave = n0 + wv * 16;
        const int arow = min(nwave + t16, N_NODES - 1);
        half8 a[6];
#pragma unroll
        for (int kb = 0; kb < 6; ++kb)
            a[kb] = *reinterpret_cast<const half8*>(aggH + (size_t)arow * 192 + kb * 32 + quad * 8);
#pragma unroll
        for (int nt = 0; nt < 4; ++nt) {
            const int c = nt * 16 + t16;
            const float bs = b2[c] + b2[64 + c] + b2[128 + c];
            const __half* __restrict__ bt = Wt + (size_t)c * 192 + quad * 8;
            f32x4 acc = {0.f, 0.f, 0.f, 0.f};
#pragma unroll
            for (int kb = 0; kb < 6; ++kb) {
                const half8 bfr = *reinterpret_cast<const half8*>(bt + kb * 32);
                acc = __builtin_amdgcn_mfma_f32_16x16x32_f16(a[kb], bfr, acc, 0, 0, 0);
            }
#pragma unroll
            for (int r = 0; r < 4; ++r)
                xl[(wv * 16 + quad * 4 + r) * 68 + c] = acc[r] + bs;
        }
    }
    for (int idx = t; idx < 384; idx += 256) Wl[idx] = W3[idx];
    if (t < 192) {
        const int k = t & 63, h = t >> 6;
        Wal[k * 3 + h] = W3[k * 6 + h * 2] * al3[h * 2] + W3[k * 6 + h * 2 + 1] * al3[h * 2 + 1];
        Wrl[k * 3 + h] = W3[k * 6 + h * 2] * ar3[h * 2] + W3[k * 6 + h * 2 + 1] * ar3[h * 2 + 1];
    }
    __syncthreads();

#pragma unroll
    for (int hp = 0; hp < 2; ++hp) {
        const int i = (t >> 3) + hp * 32;
        const int slot = t & 7;
        if (i < nvalid && slot < 6) {
            float acc = 0.f;
#pragma unroll
            for (int k4 = 0; k4 < 16; ++k4) {
                const float4 xv = *reinterpret_cast<const float4*>(&xl[i * 68 + 4 * k4]);
                acc += Wl[(4 * k4 + 0) * 6 + slot] * xv.x;
                acc += Wl[(4 * k4 + 1) * 6 + slot] * xv.y;
                acc += Wl[(4 * k4 + 2) * 6 + slot] * xv.z;
                acc += Wl[(4 * k4 + 3) * 6 + slot] * xv.w;
            }
            reinterpret_cast<__half*>(feat3p + (size_t)(n0 + i) * 8)[6 + slot] = __float2half(acc);
        }
        if (t < 192) {
            const int ii = t / 6 + hp * 32, ss = t % 6;
            if (ii < nvalid) {
                const int hh = (ss < 3) ? ss : ss - 3;
                const float* __restrict__ wt = (ss < 3) ? Wal : Wrl;
                float acc = 0.f;
#pragma unroll 4
                for (int k = 0; k < 64; ++k) acc += xl[ii * 68 + k] * wt[k * 3 + hh];
                if (ss < 3) feat3p[(size_t)(n0 + ii) * 8 + hh] = acc;   // el3 f32 at 0..2
                else        er3[(size_t)(n0 + ii) * 4 + hh] = acc;
            }
        }
    }
}

// ---------------- layer-3 aggregation: 4-edge batch, 32-bit offsets ----------
__global__ void __launch_bounds__(256, 4) k_agg3(const float* __restrict__ feat3p,
                                                 const float* __restrict__ er3,
                                                 const float* __restrict__ b3,
                                                 const int* __restrict__ rowp,
                                                 const int* __restrict__ col,
                                                 float* __restrict__ out) {
    const int tid = threadIdx.x;
    const int wv = tid >> 6;
    const int lane = tid & 63;
    const int q = lane >> 4;
    const int ql = lane & 15;
    const int n = (blockIdx.x * 4 + wv) * 4 + q;   // grid exact: 3125*16 = 50000
    const int jb = rowp[n], je = rowp[n + 1];
    const float4 er4 = *reinterpret_cast<const float4*>(er3 + (size_t)n * 4);
    const char* __restrict__ fb = (const char*)feat3p;

    float acc[6];
#pragma unroll
    for (int j = 0; j < 6; ++j) acc[j] = 0.f;
    float sw0 = 0.f, sw1 = 0.f, sw2 = 0.f;

    for (int e = jb + ql; e < je; e += 64) {
        const int eb = e + 16, ec = e + 32, ed = e + 48;
        const bool vb = (eb < je), vc = (ec < je), vd = (ed < je);
        const int sa = col[e];
        const int offa = sa << 5;
        const int offb = (vb ? col[eb] : sa) << 5;
        const int offc = (vc ? col[ec] : sa) << 5;
        const int offd = (vd ? col[ed] : sa) << 5;
        const float4 fa1 = *reinterpret_cast<const float4*>(fb + offa);
        const float2 fb1 = *reinterpret_cast<const float2*>(fb + offa + 16);
        const float4 fa2 = *reinterpret_cast<const float4*>(fb + offb);
        const float2 fb2 = *reinterpret_cast<const float2*>(fb + offb + 16);
        const float4 fa3 = *reinterpret_cast<const float4*>(fb + offc);
        const float2 fb3 = *reinterpret_cast<const float2*>(fb + offc + 16);
        const float4 fa4 = *reinterpret_cast<const float4*>(fb + offd);
        const float2 fb4 = *reinterpret_cast<const float2*>(fb + offd + 16);
        const float mb = vb ? 1.f : 0.f, mc = vc ? 1.f : 0.f, md = vd ? 1.f : 0.f;
        const float w10 = __expf(lrelu(fa1.x + er4.x));
        const float w11 = __expf(lrelu(fa1.y + er4.y));
        const float w12 = __expf(lrelu(fa1.z + er4.z));
        const float w20 = __expf(lrelu(fa2.x + er4.x)) * mb;
        const float w21 = __expf(lrelu(fa2.y + er4.y)) * mb;
        const float w22 = __expf(lrelu(fa2.z + er4.z)) * mb;
        const float w30 = __expf(lrelu(fa3.x + er4.x)) * mc;
        const float w31 = __expf(lrelu(fa3.y + er4.y)) * mc;
        const float w32 = __expf(lrelu(fa3.z + er4.z)) * mc;
        const float w40 = __expf(lrelu(fa4.x + er4.x)) * md;
        const float w41 = __expf(lrelu(fa4.y + er4.y)) * md;
        const float w42 = __expf(lrelu(fa4.z + er4.z)) * md;
        sw0 += (w10 + w20) + (w30 + w40);
        sw1 += (w11 + w21) + (w31 + w41);
        sw2 += (w12 + w22) + (w32 + w42);
        const float2 f01a = h2f(fa1.w), f23a = h2f(fb1.x), f45a = h2f(fb1.y);
        const float2 f01b = h2f(fa2.w), f23b = h2f(fb2.x), f45b = h2f(fb2.y);
        const float2 f01c = h2f(fa3.w), f23c = h2f(fb3.x), f45c = h2f(fb3.y);
        const float2 f01d = h2f(fa4.w), f23d = h2f(fb4.x), f45d = h2f(fb4.y);
        acc[0] += (w10 * f01a.x + w20 * f01b.x) + (w30 * f01c.x + w40 * f01d.x);
        acc[1] += (w10 * f01a.y + w20 * f01b.y) + (w30 * f01c.y + w40 * f01d.y);
        acc[2] += (w11 * f23a.x + w21 * f23b.x) + (w31 * f23c.x + w41 * f23d.x);
        acc[3] += (w11 * f23a.y + w21 * f23b.y) + (w31 * f23c.y + w41 * f23d.y);
        acc[4] += (w12 * f45a.x + w22 * f45b.x) + (w32 * f45c.x + w42 * f45d.x);
        acc[5] += (w12 * f45a.y + w22 * f45b.y) + (w32 * f45c.y + w42 * f45d.y);
    }
#pragma unroll
    for (int off = 1; off < 16; off <<= 1) {
        sw0 += __shfl_xor(sw0, off);
        sw1 += __shfl_xor(sw1, off);
        sw2 += __shfl_xor(sw2, off);
#pragma unroll
        for (int j = 0; j < 6; ++j) acc[j] += __shfl_xor(acc[j], off);
    }
    if (ql == 0) {
        const bool has = (je > jb);
        const float i0 = has ? 1.f / sw0 : 0.f;
        const float i1 = has ? 1.f / sw1 : 0.f;
        const float i2 = has ? 1.f / sw2 : 0.f;
        const float o0 = acc[0] * i0 + acc[2] * i1 + acc[4] * i2 + b3[0] + b3[2] + b3[4];
        const float o1 = acc[1] * i0 + acc[3] * i1 + acc[5] * i2 + b3[1] + b3[3] + b3[5];
        *reinterpret_cast<float2*>(out + (size_t)n * 2) = make_float2(o0, o1);
    }
}

extern "C" void kernel_launch(void* const* d_in, const int* in_sizes, int n_in,
                              void* d_out, int out_size, void* d_ws, size_t ws_size,
                              hipStream_t stream) {
    const float* feats = (const float*)d_in[0];
    const int* src = (const int*)d_in[1];
    const int* dst = (const int*)d_in[2];
    const float* W1 = (const float*)d_in[3];
    const float* al1 = (const float*)d_in[4];
    const float* ar1 = (const float*)d_in[5];
    const float* b1 = (const float*)d_in[6];
    const float* W2 = (const float*)d_in[7];
    const float* al2 = (const float*)d_in[8];
    const float* ar2 = (const float*)d_in[9];
    const float* b2 = (const float*)d_in[10];
    const float* W3 = (const float*)d_in[11];
    const float* al3 = (const float*)d_in[12];
    const float* ar3 = (const float*)d_in[13];
    const float* b3 = (const float*)d_in[14];
    float* out = (float*)d_out;

    char* ws = (char*)d_ws;
    size_t off = 0;
    auto alloc = [&](size_t bytes) {
        void* p = ws + off;
        off += (bytes + 255) & ~(size_t)255;
        return p;
    };
    __half* aggH = (__half*)alloc((size_t)N_NODES * 192 * 2);    // L2 agg fp16 [N][192]
    __half* hbufH = (__half*)alloc((size_t)N_NODES * 64 * 2);    // fp16 L1 hidden
    float* xph = (float*)alloc((size_t)N_NODES * 8 * 4);         // packed el1(f32)+x(f16)
    float* el = (float*)alloc((size_t)N_NODES * 4 * 4);
    float* er = (float*)alloc((size_t)N_NODES * 4 * 4);
    int* bcnt = (int*)alloc(512 * 4);                            // bcnt[256] + bfill[256]
    int* bfill = bcnt + 256;
    int* rowp = (int*)alloc((size_t)(N_NODES + 1) * 4);
    int* col = (int*)alloc((size_t)N_EDGES * 4);
    unsigned int* stage = (unsigned int*)alloc((size_t)N_EDGES * 4);
    __half* Wt16 = (__half*)alloc((size_t)64 * 192 * 2);         // 24 KB fp16 W2^T
    float* Wa2 = (float*)alloc(256 * 4);
    float* Wr2 = (float*)alloc(256 * 4);
    float* feat3p = (float*)alloc((size_t)N_NODES * 8 * 4);      // packed el3(f32)+feat(f16)
    (void)ws_size;

    const int ab = N_NODES / 4;             // k_aggw64: 4 waves/block
    const int qb = N_NODES / 16;            // 16 nodes/block kernels
    const int lb = (N_NODES + 63) / 64;     // k_l23: 64 nodes/block

    // ---- CSR build + front prep (round-4 two-phase, bucket-localized) ----
    hipMemsetAsync(bcnt, 0, 512 * 4, stream);
    k_front<<<NB_BIN + NB_EL + NB_PW + 1, 256, 0, stream>>>(
        dst, bcnt, feats, W1, al1, ar1, xph, er, W2, Wt16, al2, ar2, Wa2, Wr2);
    k_bin<<<NB_BIN, 256, 0, stream>>>(src, dst, bcnt, bfill, stage);
    k_bscatter2<<<NBKT, 256, 0, stream>>>(stage, bcnt, rowp, col);

    // ---- layer 1 (agg + GEMM fused) ----
    k_l1<<<qb, 256, 0, stream>>>(xph, er, rowp, col, W1, b1, Wa2, Wr2, hbufH, el, er);

    // ---- layer 2 aggregation ----
    k_aggw64<<<ab, 256, 0, stream>>>(hbufH, el, er, rowp, col, aggH);

    // ---- layer-2 GEMM + layer-3 features (fused) ----
    k_l23<<<lb, 256, 0, stream>>>(aggH, Wt16, b2, W3, al3, ar3, feat3p, er);

    // ---- layer 3 aggregation ----
    k_agg3<<<qb, 256, 0, stream>>>(feat3p, er, b3, rowp, col, out);
}

// Round 7
// 209.769 us; speedup vs baseline: 1.2643x; 1.0454x over previous
//
#include <hip/hip_runtime.h>
#include <hip/hip_fp16.h>

#define N_NODES 50000
#define N_EDGES 800000
#define NBKT 196            // ceil(50000 / 256) coarse buckets (dst >> 8)
#define BCAP 4480           // fixed bucket capacity: mean 4083, sd 64 -> +6 sigma
#define EPB_BIN 4096        // edges per staging block
#define NB_BIN ((N_EDGES + EPB_BIN - 1) / EPB_BIN)   // 196
#define NB_EL 196           // ceil(50000/256) blocks for el9p role
#define NB_PW 48            // 64*192/256 blocks for prepW role

typedef _Float16 half8 __attribute__((ext_vector_type(8)));
typedef float f32x4 __attribute__((ext_vector_type(4)));

static __device__ __forceinline__ float lrelu(float x) { return fmaxf(x, 0.2f * x); }

static __device__ __forceinline__ float2 h2f(float bits) {
    union { float f; __half2 h; } u;
    u.f = bits;
    return __half22float2(u.h);
}
static __device__ __forceinline__ float f2h2(float a, float b) {
    union { float f; __half2 h; } u;
    u.h = __floats2half2_rn(a, b);
    return u.f;
}

// ---------------- fused front kernel: stage | el9p | prepW | prepA ----------
// Staging role replaces the old count role: fixed-capacity buckets mean the
// count pass IS the placement pass (k_bin deleted; one 6.4MB edge sweep saved).
__global__ void __launch_bounds__(256) k_front(const int* __restrict__ src,
                                               const int* __restrict__ dst,
                                               int* __restrict__ bfill,
                                               unsigned int* __restrict__ stage,
                                               const float* __restrict__ x,
                                               const float* __restrict__ W1,
                                               const float* __restrict__ al1,
                                               const float* __restrict__ ar1,
                                               float* __restrict__ xph,
                                               float* __restrict__ er,
                                               const float* __restrict__ W2,
                                               __half* __restrict__ Wt16,
                                               const float* __restrict__ al2,
                                               const float* __restrict__ ar2,
                                               float* __restrict__ Wa2,
                                               float* __restrict__ Wr2) {
    __shared__ int lcnt[NBKT];
    __shared__ int gb[NBKT];
    __shared__ int lf[NBKT];
    __shared__ float sWa[9 * 3];
    __shared__ float sWr[9 * 3];
    const int t = threadIdx.x;
    const int b = blockIdx.x;

    if (b < NB_BIN) {
        // ---- role: stage edges into fixed-capacity buckets ----
        const int e0 = b * EPB_BIN;
        for (int i = t; i < NBKT; i += 256) lcnt[i] = 0;
        __syncthreads();
        int dcache[16];
#pragma unroll
        for (int i = 0; i < 16; ++i) {
            const int e = e0 + i * 256 + t;
            if (e < N_EDGES) {
                const int d = dst[e];
                dcache[i] = d;
                atomicAdd(&lcnt[d >> 8], 1);
            } else dcache[i] = -1;
        }
        __syncthreads();
        for (int i = t; i < NBKT; i += 256) {
            gb[i] = i * BCAP + atomicAdd(&bfill[i], lcnt[i]);
            lf[i] = 0;
        }
        __syncthreads();
#pragma unroll
        for (int i = 0; i < 16; ++i) {
            const int e = e0 + i * 256 + t;
            if (e < N_EDGES) {
                const int d = dcache[i];
                const int bk = d >> 8;
                const int r = atomicAdd(&lf[bk], 1);
                stage[gb[bk] + r] = (unsigned int)src[e] | ((unsigned int)(d & 255) << 16);
            }
        }
        return;
    }
    if (b < NB_BIN + NB_EL) {
        // ---- role: layer-1 packed features + er ----
        if (t < 27) {
            const int h = t / 9, k = t % 9;
            float sa = 0.f, sr = 0.f;
            for (int f = 0; f < 64; ++f) {
                const float w = W1[k * 192 + h * 64 + f];
                sa += w * al1[h * 64 + f];
                sr += w * ar1[h * 64 + f];
            }
            sWa[k * 3 + h] = sa;
            sWr[k * 3 + h] = sr;
        }
        __syncthreads();
        const int n = (b - NB_BIN) * 256 + t;
        if (n >= N_NODES) return;
        const float* __restrict__ xr = x + (size_t)n * 9;
        float xv[9];
        float a0 = 0.f, a1 = 0.f, a2 = 0.f, r0 = 0.f, r1 = 0.f, r2 = 0.f;
#pragma unroll
        for (int k = 0; k < 9; ++k) {
            xv[k] = xr[k];
            a0 += xv[k] * sWa[k * 3 + 0];
            a1 += xv[k] * sWa[k * 3 + 1];
            a2 += xv[k] * sWa[k * 3 + 2];
            r0 += xv[k] * sWr[k * 3 + 0];
            r1 += xv[k] * sWr[k * 3 + 1];
            r2 += xv[k] * sWr[k * 3 + 2];
        }
        float* __restrict__ xo = xph + (size_t)n * 8;
        *reinterpret_cast<float4*>(xo) = make_float4(a0, a1, a2, f2h2(xv[0], xv[1]));
        *reinterpret_cast<float4*>(xo + 4) =
            make_float4(f2h2(xv[2], xv[3]), f2h2(xv[4], xv[5]),
                        f2h2(xv[6], xv[7]), f2h2(xv[8], 0.f));
        *reinterpret_cast<float4*>(er + (size_t)n * 4) = make_float4(r0, r1, r2, 0.f);
        return;
    }
    if (b < NB_BIN + NB_EL + NB_PW) {
        // ---- role: W2 -> fp16 effective-transpose table ----
        const int idx = (b - (NB_BIN + NB_EL)) * 256 + t;
        if (idx < 64 * 192) {
            const int n = idx / 192, ke = idx % 192;
            Wt16[idx] = __float2half(W2[(ke & 63) * 192 + (ke >> 6) * 64 + n]);
        }
        return;
    }
    // ---- role: Wa2/Wr2 precompute ----
    if (t < 192) {
        const int h = t >> 6, k = t & 63;
        float sa = 0.f, sr = 0.f;
        for (int f = 0; f < 64; ++f) {
            const float w = W2[k * 192 + h * 64 + f];
            sa += w * al2[h * 64 + f];
            sr += w * ar2[h * 64 + f];
        }
        Wa2[k * 4 + h] = sa;
        Wr2[k * 4 + h] = sr;
        if (h == 0) { Wa2[k * 4 + 3] = 0.f; Wr2[k * 4 + 3] = 0.f; }
    }
}

// ---------------- per bucket scatter (512 threads; bfill totals scan) --------
__global__ void __launch_bounds__(512) k_bscatter2(const unsigned int* __restrict__ stage,
                                                   const int* __restrict__ bfill,
                                                   int* __restrict__ rowp,
                                                   int* __restrict__ col) {
    __shared__ int lcnt[256];
    __shared__ int lpos[256];
    __shared__ int sexc[256];
    __shared__ int sscan[256];
    const int t = threadIdx.x;
    const int b = blockIdx.x;
    const int n0 = b << 8;
    // inclusive scan of final bucket totals -> global base for this bucket
    int bv = 0;
    if (t < 256) {
        bv = (t < NBKT) ? bfill[t] : 0;
        sscan[t] = bv;
        lcnt[t] = 0;
    }
    __syncthreads();
    for (int off = 1; off < 256; off <<= 1) {
        int u = 0;
        if (t < 256 && t >= off) u = sscan[t - off];
        __syncthreads();
        if (t < 256) sscan[t] += u;
        __syncthreads();
    }
    const int base = (b == 0) ? 0 : sscan[b - 1];
    const int cnt = bfill[b];
    const unsigned int* __restrict__ st = stage + (size_t)b * BCAP;

    for (int j = t; j < cnt; j += 512)
        atomicAdd(&lcnt[(st[j] >> 16) & 255], 1);
    __syncthreads();
    int v = 0;
    if (t < 256) { v = lcnt[t]; lpos[t] = v; }
    __syncthreads();
    for (int off = 1; off < 256; off <<= 1) {
        int u = 0;
        if (t < 256 && t >= off) u = lpos[t - off];
        __syncthreads();
        if (t < 256) lpos[t] += u;
        __syncthreads();
    }
    if (t < 256) {
        sexc[t] = lpos[t] - v;
        if (n0 + t < N_NODES) rowp[n0 + t] = base + sexc[t];
        lcnt[t] = 0;   // reuse as fill counters
    }
    if (b == NBKT - 1 && t == 0) rowp[N_NODES] = N_EDGES;
    __syncthreads();
    for (int j = t; j < cnt; j += 512) {
        const unsigned int e = st[j];
        const int local = (int)(e >> 16) & 255;
        const int r = atomicAdd(&lcnt[local], 1);
        col[base + sexc[local] + r] = (int)(e & 0xFFFFu);
    }
}

// ---------------- fused L1: agg + gemm2 (2-batch, 32-bit offsets) ------------
__global__ void __launch_bounds__(256, 6) k_l1(const float* __restrict__ xph,
                                               const float* __restrict__ er_in,
                                               const int* __restrict__ rowp,
                                               const int* __restrict__ col,
                                               const float* __restrict__ W1,
                                               const float* __restrict__ b1,
                                               const float* __restrict__ Wa2,
                                               const float* __restrict__ Wr2,
                                               __half* __restrict__ hout,
                                               float* __restrict__ el,
                                               float* __restrict__ er_out) {
    __shared__ union {
        float At[16 * 28];          // agg -> gemm handoff (dead after part compute)
        float vbuf[16][72];         // gemm epilogue staging (aliases At; sync between)
    } u;
    __shared__ float part[3][16][64];
    const int t = threadIdx.x;
    const int wv = t >> 6;
    const int lane = t & 63;
    const int q = lane >> 4;            // node slot within wave
    const int ql = lane & 15;           // lane within quarter
    const int li = wv * 4 + q;          // local node 0..15
    const int nbase = blockIdx.x * 16;  // 3125 * 16 = 50000 exact
    const int n = nbase + li;
    const char* __restrict__ xb = (const char*)xph;

    // ---- aggregation (lane-per-edge, 2-edge batch) ----
    {
        const int jb = rowp[n], je = rowp[n + 1];
        const float4 er4 = *reinterpret_cast<const float4*>(er_in + (size_t)n * 4);
        float acc[27];
#pragma unroll
        for (int j = 0; j < 27; ++j) acc[j] = 0.f;
        float sw0 = 0.f, sw1 = 0.f, sw2 = 0.f;

        for (int e = jb + ql; e < je; e += 32) {
            const int e2 = e + 16;
            const bool v2 = (e2 < je);
            const int off1 = col[e] << 5;
            const int off2 = (v2 ? col[e2] : col[e]) << 5;
            const float4 xa1 = *reinterpret_cast<const float4*>(xb + off1);
            const float4 xb1 = *reinterpret_cast<const float4*>(xb + off1 + 16);
            const float4 xa2 = *reinterpret_cast<const float4*>(xb + off2);
            const float4 xb2 = *reinterpret_cast<const float4*>(xb + off2 + 16);
            const float m2 = v2 ? 1.f : 0.f;
            const float w10 = __expf(lrelu(xa1.x + er4.x));
            const float w11 = __expf(lrelu(xa1.y + er4.y));
            const float w12 = __expf(lrelu(xa1.z + er4.z));
            const float w20 = __expf(lrelu(xa2.x + er4.x)) * m2;
            const float w21 = __expf(lrelu(xa2.y + er4.y)) * m2;
            const float w22 = __expf(lrelu(xa2.z + er4.z)) * m2;
            sw0 += w10 + w20; sw1 += w11 + w21; sw2 += w12 + w22;
            const float2 p10 = h2f(xa1.w), p11 = h2f(xb1.x), p12 = h2f(xb1.y),
                         p13 = h2f(xb1.z), p14 = h2f(xb1.w);
            const float2 p20 = h2f(xa2.w), p21 = h2f(xb2.x), p22 = h2f(xb2.y),
                         p23 = h2f(xb2.z), p24 = h2f(xb2.w);
            const float x1[9] = {p10.x, p10.y, p11.x, p11.y, p12.x, p12.y, p13.x, p13.y, p14.x};
            const float x2[9] = {p20.x, p20.y, p21.x, p21.y, p22.x, p22.y, p23.x, p23.y, p24.x};
#pragma unroll
            for (int k = 0; k < 9; ++k) {
                acc[0 + k]  += w10 * x1[k] + w20 * x2[k];
                acc[9 + k]  += w11 * x1[k] + w21 * x2[k];
                acc[18 + k] += w12 * x1[k] + w22 * x2[k];
            }
        }
#pragma unroll
        for (int off = 1; off < 16; off <<= 1) {
            sw0 += __shfl_xor(sw0, off);
            sw1 += __shfl_xor(sw1, off);
            sw2 += __shfl_xor(sw2, off);
#pragma unroll
            for (int j = 0; j < 27; ++j) acc[j] += __shfl_xor(acc[j], off);
        }
        if (ql == 0) {
            const bool has = (je > jb);
            const float i0 = has ? 1.f / sw0 : 0.f;
            const float i1 = has ? 1.f / sw1 : 0.f;
            const float i2 = has ? 1.f / sw2 : 0.f;
            float* __restrict__ ao = u.At + li * 28;
#pragma unroll
            for (int k = 0; k < 9; ++k) {
                ao[k] = acc[k] * i0;
                ao[9 + k] = acc[9 + k] * i1;
                ao[18 + k] = acc[18 + k] * i2;
            }
        }
    }
    __syncthreads();

    // ---- GEMM (h = wave id, c = lane) ----
    {
        const int h = wv;               // 0..3; h==3 idle for partials
        const int c = lane;
        if (h < 3) {
            float wreg[9];
#pragma unroll
            for (int k = 0; k < 9; ++k) wreg[k] = W1[k * 192 + h * 64 + c];
#pragma unroll
            for (int i = 0; i < 16; ++i) {
                const float* __restrict__ arp = u.At + i * 28 + h * 9;
                float acc = 0.f;
#pragma unroll
                for (int k = 0; k < 9; ++k) acc += arp[k] * wreg[k];
                part[h][i][c] = acc;
            }
        }
        __syncthreads();
        const float bsum = b1[c] + b1[64 + c] + b1[128 + c];
        for (int idx = t; idx < 1024; idx += 256) {
            const int i = idx >> 6, cc = idx & 63;  // cc == c (stride 256)
            const float v = part[0][i][cc] + part[1][i][cc] + part[2][i][cc] + bsum;
            hout[(size_t)(nbase + i) * 64 + cc] = __float2half(v);
            u.vbuf[i][cc] = v;           // aliases At — legal: At dead, sync above
        }
        __syncthreads();
        if (t < 96) {
            const int i = t / 6, r = t % 6;
            const int h3 = (r < 3) ? r : r - 3;
            const float* __restrict__ tab = (r < 3) ? Wa2 : Wr2;
            float s = 0.f;
#pragma unroll 8
            for (int c2 = 0; c2 < 64; ++c2) s += u.vbuf[i][c2] * tab[c2 * 4 + h3];
            if (r < 3) el[(size_t)(nbase + i) * 4 + h3] = s;
            else       er_out[(size_t)(nbase + i) * 4 + h3] = s;
        }
    }
}

// ---------------- L2 aggregation v4: packed LDS float4, 32-bit offsets -------
__global__ void __launch_bounds__(256, 8) k_aggw64(const __half* __restrict__ x,
                                                   const float* __restrict__ el,
                                                   const float* __restrict__ er,
                                                   const int* __restrict__ rowp,
                                                   const int* __restrict__ col,
                                                   __half* __restrict__ agg) {
    const int wv = threadIdx.x >> 6;
    const int lane = threadIdx.x & 63;
    const int n = blockIdx.x * 4 + wv;          // grid exact
    const int jb = rowp[n], je = rowp[n + 1];

    __shared__ float4 wbuf4[4][64];             // (w0, w1, w2, bitcast(row byte off))
    const float4 er4 = *reinterpret_cast<const float4*>(er + (size_t)n * 4);
    const int p = lane >> 5;
    const int foff = (lane & 31) * 4;           // byte offset of this lane's half2
    const char* __restrict__ xbase = (const char*)x;
    const char* __restrict__ elbase = (const char*)el;
    float a00 = 0.f, a01 = 0.f, a02 = 0.f;
    float a10 = 0.f, a11 = 0.f, a12 = 0.f;
    float sw0 = 0.f, sw1 = 0.f, sw2 = 0.f;

    for (int c0 = jb; c0 < je; c0 += 64) {
        const int cnt = min(64, je - c0);
        if (lane < cnt) {
            const int s = col[c0 + lane];
            const float4 e4 = *reinterpret_cast<const float4*>(elbase + (s << 4));
            const float w0 = __expf(lrelu(e4.x + er4.x));
            const float w1 = __expf(lrelu(e4.y + er4.y));
            const float w2 = __expf(lrelu(e4.z + er4.z));
            wbuf4[wv][lane] = make_float4(w0, w1, w2, __int_as_float(s << 7));
            sw0 += w0; sw1 += w1; sw2 += w2;
        }
        __builtin_amdgcn_wave_barrier();   // LDS written by same wave; no block sync needed
        int e = 0;
        for (; e + 4 <= cnt; e += 4) {
            const float4 q1 = wbuf4[wv][e + p];
            const float4 q2 = wbuf4[wv][e + 2 + p];
            const float2 f1 = __half22float2(*reinterpret_cast<const __half2*>(
                xbase + (__float_as_int(q1.w) + foff)));
            const float2 f2 = __half22float2(*reinterpret_cast<const __half2*>(
                xbase + (__float_as_int(q2.w) + foff)));
            a00 += q1.x * f1.x + q2.x * f2.x;
            a01 += q1.y * f1.x + q2.y * f2.x;
            a02 += q1.z * f1.x + q2.z * f2.x;
            a10 += q1.x * f1.y + q2.x * f2.y;
            a11 += q1.y * f1.y + q2.y * f2.y;
            a12 += q1.z * f1.y + q2.z * f2.y;
        }
        if (e + p < cnt) {
            const float4 q1 = wbuf4[wv][e + p];
            const float2 f1 = __half22float2(*reinterpret_cast<const __half2*>(
                xbase + (__float_as_int(q1.w) + foff)));
            a00 += q1.x * f1.x; a01 += q1.y * f1.x; a02 += q1.z * f1.x;
            a10 += q1.x * f1.y; a11 += q1.y * f1.y; a12 += q1.z * f1.y;
        }
        if (e + 2 + p < cnt) {
            const float4 q2 = wbuf4[wv][e + 2 + p];
            const float2 f2 = __half22float2(*reinterpret_cast<const __half2*>(
                xbase + (__float_as_int(q2.w) + foff)));
            a00 += q2.x * f2.x; a01 += q2.y * f2.x; a02 += q2.z * f2.x;
            a10 += q2.x * f2.y; a11 += q2.y * f2.y; a12 += q2.z * f2.y;
        }
    }
    a00 += __shfl_xor(a00, 32); a01 += __shfl_xor(a01, 32); a02 += __shfl_xor(a02, 32);
    a10 += __shfl_xor(a10, 32); a11 += __shfl_xor(a11, 32); a12 += __shfl_xor(a12, 32);
#pragma unroll
    for (int off = 32; off > 0; off >>= 1) {
        sw0 += __shfl_xor(sw0, off);
        sw1 += __shfl_xor(sw1, off);
        sw2 += __shfl_xor(sw2, off);
    }
    if (lane < 32) {
        const int f0 = (lane & 31) * 2;
        __half* __restrict__ ao = agg + (size_t)n * 192;
        if (je > jb) {
            const float i0 = 1.f / sw0, i1 = 1.f / sw1, i2 = 1.f / sw2;
            *reinterpret_cast<__half2*>(ao + f0) = __floats2half2_rn(a00 * i0, a10 * i0);
            *reinterpret_cast<__half2*>(ao + 64 + f0) = __floats2half2_rn(a01 * i1, a11 * i1);
            *reinterpret_cast<__half2*>(ao + 128 + f0) = __floats2half2_rn(a02 * i2, a12 * i2);
        } else {
            const __half2 z = __floats2half2_rn(0.f, 0.f);
            *reinterpret_cast<__half2*>(ao + f0) = z;
            *reinterpret_cast<__half2*>(ao + 64 + f0) = z;
            *reinterpret_cast<__half2*>(ao + 128 + f0) = z;
        }
    }
}

// ---------------- fused L2 GEMM (MFMA) + layer-3 features (LDS handoff) ------
__global__ void __launch_bounds__(256) k_l23(const __half* __restrict__ aggH,
                                             const __half* __restrict__ Wt,
                                             const float* __restrict__ b2,
                                             const float* __restrict__ W3,
                                             const float* __restrict__ al3,
                                             const float* __restrict__ ar3,
                                             float* __restrict__ feat3p,
                                             float* __restrict__ er3) {
    __shared__ float xl[64 * 68];
    __shared__ float Wl[64 * 6];
    __shared__ float Wal[64 * 3];
    __shared__ float Wrl[64 * 3];
    const int t = threadIdx.x;
    const int n0 = blockIdx.x * 64;             // 782 blocks; last has nvalid=16
    const int nvalid = min(64, N_NODES - n0);

    {
        const int wv = t >> 6;
        const int lane = t & 63;
        const int quad = lane >> 4;
        const int t16 = lane & 15;
        const int nwave = n0 + wv * 16;
        const int arow = min(nwave + t16, N_NODES - 1);
        half8 a[6];
#pragma unroll
        for (int kb = 0; kb < 6; ++kb)
            a[kb] = *reinterpret_cast<const half8*>(aggH + (size_t)arow * 192 + kb * 32 + quad * 8);
#pragma unroll
        for (int nt = 0; nt < 4; ++nt) {
            const int c = nt * 16 + t16;
            const float bs = b2[c] + b2[64 + c] + b2[128 + c];
            const __half* __restrict__ bt = Wt + (size_t)c * 192 + quad * 8;
            f32x4 acc = {0.f, 0.f, 0.f, 0.f};
#pragma unroll
            for (int kb = 0; kb < 6; ++kb) {
                const half8 bfr = *reinterpret_cast<const half8*>(bt + kb * 32);
                acc = __builtin_amdgcn_mfma_f32_16x16x32_f16(a[kb], bfr, acc, 0, 0, 0);
            }
#pragma unroll
            for (int r = 0; r < 4; ++r)
                xl[(wv * 16 + quad * 4 + r) * 68 + c] = acc[r] + bs;
        }
    }
    for (int idx = t; idx < 384; idx += 256) Wl[idx] = W3[idx];
    if (t < 192) {
        const int k = t & 63, h = t >> 6;
        Wal[k * 3 + h] = W3[k * 6 + h * 2] * al3[h * 2] + W3[k * 6 + h * 2 + 1] * al3[h * 2 + 1];
        Wrl[k * 3 + h] = W3[k * 6 + h * 2] * ar3[h * 2] + W3[k * 6 + h * 2 + 1] * ar3[h * 2 + 1];
    }
    __syncthreads();

#pragma unroll
    for (int hp = 0; hp < 2; ++hp) {
        const int i = (t >> 3) + hp * 32;
        const int slot = t & 7;
        if (i < nvalid && slot < 6) {
            float acc = 0.f;
#pragma unroll
            for (int k4 = 0; k4 < 16; ++k4) {
                const float4 xv = *reinterpret_cast<const float4*>(&xl[i * 68 + 4 * k4]);
                acc += Wl[(4 * k4 + 0) * 6 + slot] * xv.x;
                acc += Wl[(4 * k4 + 1) * 6 + slot] * xv.y;
                acc += Wl[(4 * k4 + 2) * 6 + slot] * xv.z;
                acc += Wl[(4 * k4 + 3) * 6 + slot] * xv.w;
            }
            reinterpret_cast<__half*>(feat3p + (size_t)(n0 + i) * 8)[6 + slot] = __float2half(acc);
        }
        if (t < 192) {
            const int ii = t / 6 + hp * 32, ss = t % 6;
            if (ii < nvalid) {
                const int hh = (ss < 3) ? ss : ss - 3;
                const float* __restrict__ wt = (ss < 3) ? Wal : Wrl;
                float acc = 0.f;
#pragma unroll 4
                for (int k = 0; k < 64; ++k) acc += xl[ii * 68 + k] * wt[k * 3 + hh];
                if (ss < 3) feat3p[(size_t)(n0 + ii) * 8 + hh] = acc;   // el3 f32 at 0..2
                else        er3[(size_t)(n0 + ii) * 4 + hh] = acc;
            }
        }
    }
}

// ---------------- layer-3 aggregation: 4-edge batch, 32-bit offsets ----------
__global__ void __launch_bounds__(256, 4) k_agg3(const float* __restrict__ feat3p,
                                                 const float* __restrict__ er3,
                                                 const float* __restrict__ b3,
                                                 const int* __restrict__ rowp,
                                                 const int* __restrict__ col,
                                                 float* __restrict__ out) {
    const int tid = threadIdx.x;
    const int wv = tid >> 6;
    const int lane = tid & 63;
    const int q = lane >> 4;
    const int ql = lane & 15;
    const int n = (blockIdx.x * 4 + wv) * 4 + q;   // grid exact: 3125*16 = 50000
    const int jb = rowp[n], je = rowp[n + 1];
    const float4 er4 = *reinterpret_cast<const float4*>(er3 + (size_t)n * 4);
    const char* __restrict__ fb = (const char*)feat3p;

    float acc[6];
#pragma unroll
    for (int j = 0; j < 6; ++j) acc[j] = 0.f;
    float sw0 = 0.f, sw1 = 0.f, sw2 = 0.f;

    for (int e = jb + ql; e < je; e += 64) {
        const int eb = e + 16, ec = e + 32, ed = e + 48;
        const bool vb = (eb < je), vc = (ec < je), vd = (ed < je);
        const int sa = col[e];
        const int offa = sa << 5;
        const int offb = (vb ? col[eb] : sa) << 5;
        const int offc = (vc ? col[ec] : sa) << 5;
        const int offd = (vd ? col[ed] : sa) << 5;
        const float4 fa1 = *reinterpret_cast<const float4*>(fb + offa);
        const float2 fb1 = *reinterpret_cast<const float2*>(fb + offa + 16);
        const float4 fa2 = *reinterpret_cast<const float4*>(fb + offb);
        const float2 fb2 = *reinterpret_cast<const float2*>(fb + offb + 16);
        const float4 fa3 = *reinterpret_cast<const float4*>(fb + offc);
        const float2 fb3 = *reinterpret_cast<const float2*>(fb + offc + 16);
        const float4 fa4 = *reinterpret_cast<const float4*>(fb + offd);
        const float2 fb4 = *reinterpret_cast<const float2*>(fb + offd + 16);
        const float mb = vb ? 1.f : 0.f, mc = vc ? 1.f : 0.f, md = vd ? 1.f : 0.f;
        const float w10 = __expf(lrelu(fa1.x + er4.x));
        const float w11 = __expf(lrelu(fa1.y + er4.y));
        const float w12 = __expf(lrelu(fa1.z + er4.z));
        const float w20 = __expf(lrelu(fa2.x + er4.x)) * mb;
        const float w21 = __expf(lrelu(fa2.y + er4.y)) * mb;
        const float w22 = __expf(lrelu(fa2.z + er4.z)) * mb;
        const float w30 = __expf(lrelu(fa3.x + er4.x)) * mc;
        const float w31 = __expf(lrelu(fa3.y + er4.y)) * mc;
        const float w32 = __expf(lrelu(fa3.z + er4.z)) * mc;
        const float w40 = __expf(lrelu(fa4.x + er4.x)) * md;
        const float w41 = __expf(lrelu(fa4.y + er4.y)) * md;
        const float w42 = __expf(lrelu(fa4.z + er4.z)) * md;
        sw0 += (w10 + w20) + (w30 + w40);
        sw1 += (w11 + w21) + (w31 + w41);
        sw2 += (w12 + w22) + (w32 + w42);
        const float2 f01a = h2f(fa1.w), f23a = h2f(fb1.x), f45a = h2f(fb1.y);
        const float2 f01b = h2f(fa2.w), f23b = h2f(fb2.x), f45b = h2f(fb2.y);
        const float2 f01c = h2f(fa3.w), f23c = h2f(fb3.x), f45c = h2f(fb3.y);
        const float2 f01d = h2f(fa4.w), f23d = h2f(fb4.x), f45d = h2f(fb4.y);
        acc[0] += (w10 * f01a.x + w20 * f01b.x) + (w30 * f01c.x + w40 * f01d.x);
        acc[1] += (w10 * f01a.y + w20 * f01b.y) + (w30 * f01c.y + w40 * f01d.y);
        acc[2] += (w11 * f23a.x + w21 * f23b.x) + (w31 * f23c.x + w41 * f23d.x);
        acc[3] += (w11 * f23a.y + w21 * f23b.y) + (w31 * f23c.y + w41 * f23d.y);
        acc[4] += (w12 * f45a.x + w22 * f45b.x) + (w32 * f45c.x + w42 * f45d.x);
        acc[5] += (w12 * f45a.y + w22 * f45b.y) + (w32 * f45c.y + w42 * f45d.y);
    }
#pragma unroll
    for (int off = 1; off < 16; off <<= 1) {
        sw0 += __shfl_xor(sw0, off);
        sw1 += __shfl_xor(sw1, off);
        sw2 += __shfl_xor(sw2, off);
#pragma unroll
        for (int j = 0; j < 6; ++j) acc[j] += __shfl_xor(acc[j], off);
    }
    if (ql == 0) {
        const bool has = (je > jb);
        const float i0 = has ? 1.f / sw0 : 0.f;
        const float i1 = has ? 1.f / sw1 : 0.f;
        const float i2 = has ? 1.f / sw2 : 0.f;
        const float o0 = acc[0] * i0 + acc[2] * i1 + acc[4] * i2 + b3[0] + b3[2] + b3[4];
        const float o1 = acc[1] * i0 + acc[3] * i1 + acc[5] * i2 + b3[1] + b3[3] + b3[5];
        *reinterpret_cast<float2*>(out + (size_t)n * 2) = make_float2(o0, o1);
    }
}

extern "C" void kernel_launch(void* const* d_in, const int* in_sizes, int n_in,
                              void* d_out, int out_size, void* d_ws, size_t ws_size,
                              hipStream_t stream) {
    const float* feats = (const float*)d_in[0];
    const int* src = (const int*)d_in[1];
    const int* dst = (const int*)d_in[2];
    const float* W1 = (const float*)d_in[3];
    const float* al1 = (const float*)d_in[4];
    const float* ar1 = (const float*)d_in[5];
    const float* b1 = (const float*)d_in[6];
    const float* W2 = (const float*)d_in[7];
    const float* al2 = (const float*)d_in[8];
    const float* ar2 = (const float*)d_in[9];
    const float* b2 = (const float*)d_in[10];
    const float* W3 = (const float*)d_in[11];
    const float* al3 = (const float*)d_in[12];
    const float* ar3 = (const float*)d_in[13];
    const float* b3 = (const float*)d_in[14];
    float* out = (float*)d_out;

    char* ws = (char*)d_ws;
    size_t off = 0;
    auto alloc = [&](size_t bytes) {
        void* p = ws + off;
        off += (bytes + 255) & ~(size_t)255;
        return p;
    };
    __half* aggH = (__half*)alloc((size_t)N_NODES * 192 * 2);    // L2 agg fp16 [N][192]
    __half* hbufH = (__half*)alloc((size_t)N_NODES * 64 * 2);    // fp16 L1 hidden
    float* xph = (float*)alloc((size_t)N_NODES * 8 * 4);         // packed el1(f32)+x(f16)
    float* el = (float*)alloc((size_t)N_NODES * 4 * 4);
    float* er = (float*)alloc((size_t)N_NODES * 4 * 4);
    int* bfill = (int*)alloc(256 * 4);
    int* rowp = (int*)alloc((size_t)(N_NODES + 1) * 4);
    int* col = (int*)alloc((size_t)N_EDGES * 4);
    unsigned int* stage = (unsigned int*)alloc((size_t)NBKT * BCAP * 4);  // 3.5 MB
    __half* Wt16 = (__half*)alloc((size_t)64 * 192 * 2);         // 24 KB fp16 W2^T
    float* Wa2 = (float*)alloc(256 * 4);
    float* Wr2 = (float*)alloc(256 * 4);
    float* feat3p = (float*)alloc((size_t)N_NODES * 8 * 4);      // packed el3(f32)+feat(f16)
    (void)ws_size;

    const int ab = N_NODES / 4;             // k_aggw64: 4 waves/block
    const int qb = N_NODES / 16;            // 16 nodes/block kernels
    const int lb = (N_NODES + 63) / 64;     // k_l23: 64 nodes/block

    // ---- CSR build + front prep (single edge sweep via fixed-cap buckets) ----
    hipMemsetAsync(bfill, 0, 256 * 4, stream);
    k_front<<<NB_BIN + NB_EL + NB_PW + 1, 256, 0, stream>>>(
        src, dst, bfill, stage, feats, W1, al1, ar1, xph, er, W2, Wt16,
        al2, ar2, Wa2, Wr2);
    k_bscatter2<<<NBKT, 512, 0, stream>>>(stage, bfill, rowp, col);

    // ---- layer 1 (agg + GEMM fused) ----
    k_l1<<<qb, 256, 0, stream>>>(xph, er, rowp, col, W1, b1, Wa2, Wr2, hbufH, el, er);

    // ---- layer 2 aggregation ----
    k_aggw64<<<ab, 256, 0, stream>>>(hbufH, el, er, rowp, col, aggH);

    // ---- layer-2 GEMM + layer-3 features (fused) ----
    k_l23<<<lb, 256, 0, stream>>>(aggH, Wt16, b2, W3, al3, ar3, feat3p, er);

    // ---- layer 3 aggregation ----
    k_agg3<<<qb, 256, 0, stream>>>(feat3p, er, b3, rowp, col, out);
}

// Round 8
// 202.881 us; speedup vs baseline: 1.3072x; 1.0340x over previous
//
#include <hip/hip_runtime.h>
#include <hip/hip_fp16.h>

#define N_NODES 50000
#define N_EDGES 800000
#define NBKT 196            // ceil(50000 / 256) coarse buckets (dst >> 8)
#define BCAP 4480           // fixed bucket capacity: mean 4083, sd 64 -> +6 sigma
#define EPB_BIN 4096        // edges per staging block
#define NB_BIN ((N_EDGES + EPB_BIN - 1) / EPB_BIN)   // 196
#define NB_EL 196           // ceil(50000/256) blocks for el9p role
#define NB_PW 48            // 64*192/256 blocks for prepW role

typedef _Float16 half8 __attribute__((ext_vector_type(8)));
typedef float f32x4 __attribute__((ext_vector_type(4)));

static __device__ __forceinline__ float lrelu(float x) { return fmaxf(x, 0.2f * x); }

static __device__ __forceinline__ float2 h2f(float bits) {
    union { float f; __half2 h; } u;
    u.f = bits;
    return __half22float2(u.h);
}
static __device__ __forceinline__ float f2h2(float a, float b) {
    union { float f; __half2 h; } u;
    u.h = __floats2half2_rn(a, b);
    return u.f;
}

// ---------------- fused front kernel: stage | el9p | prepW | prepA ----------
__global__ void __launch_bounds__(256) k_front(const int* __restrict__ src,
                                               const int* __restrict__ dst,
                                               int* __restrict__ bfill,
                                               unsigned int* __restrict__ stage,
                                               const float* __restrict__ x,
                                               const float* __restrict__ W1,
                                               const float* __restrict__ al1,
                                               const float* __restrict__ ar1,
                                               float* __restrict__ xph,
                                               float* __restrict__ er,
                                               const float* __restrict__ W2,
                                               __half* __restrict__ Wt16,
                                               const float* __restrict__ al2,
                                               const float* __restrict__ ar2,
                                               float* __restrict__ Wa2,
                                               float* __restrict__ Wr2) {
    __shared__ int lcnt[NBKT];
    __shared__ int gb[NBKT];
    __shared__ int lf[NBKT];
    __shared__ float sWa[9 * 3];
    __shared__ float sWr[9 * 3];
    const int t = threadIdx.x;
    const int b = blockIdx.x;

    if (b < NB_BIN) {
        // ---- role: stage edges into fixed-capacity buckets ----
        const int e0 = b * EPB_BIN;
        for (int i = t; i < NBKT; i += 256) lcnt[i] = 0;
        __syncthreads();
        int dcache[16];
#pragma unroll
        for (int i = 0; i < 16; ++i) {
            const int e = e0 + i * 256 + t;
            if (e < N_EDGES) {
                const int d = dst[e];
                dcache[i] = d;
                atomicAdd(&lcnt[d >> 8], 1);
            } else dcache[i] = -1;
        }
        __syncthreads();
        for (int i = t; i < NBKT; i += 256) {
            gb[i] = i * BCAP + atomicAdd(&bfill[i], lcnt[i]);
            lf[i] = 0;
        }
        __syncthreads();
#pragma unroll
        for (int i = 0; i < 16; ++i) {
            const int e = e0 + i * 256 + t;
            if (e < N_EDGES) {
                const int d = dcache[i];
                const int bk = d >> 8;
                const int r = atomicAdd(&lf[bk], 1);
                stage[gb[bk] + r] = (unsigned int)src[e] | ((unsigned int)(d & 255) << 16);
            }
        }
        return;
    }
    if (b < NB_BIN + NB_EL) {
        // ---- role: layer-1 packed features + er ----
        if (t < 27) {
            const int h = t / 9, k = t % 9;
            float sa = 0.f, sr = 0.f;
            for (int f = 0; f < 64; ++f) {
                const float w = W1[k * 192 + h * 64 + f];
                sa += w * al1[h * 64 + f];
                sr += w * ar1[h * 64 + f];
            }
            sWa[k * 3 + h] = sa;
            sWr[k * 3 + h] = sr;
        }
        __syncthreads();
        const int n = (b - NB_BIN) * 256 + t;
        if (n >= N_NODES) return;
        const float* __restrict__ xr = x + (size_t)n * 9;
        float xv[9];
        float a0 = 0.f, a1 = 0.f, a2 = 0.f, r0 = 0.f, r1 = 0.f, r2 = 0.f;
#pragma unroll
        for (int k = 0; k < 9; ++k) {
            xv[k] = xr[k];
            a0 += xv[k] * sWa[k * 3 + 0];
            a1 += xv[k] * sWa[k * 3 + 1];
            a2 += xv[k] * sWa[k * 3 + 2];
            r0 += xv[k] * sWr[k * 3 + 0];
            r1 += xv[k] * sWr[k * 3 + 1];
            r2 += xv[k] * sWr[k * 3 + 2];
        }
        float* __restrict__ xo = xph + (size_t)n * 8;
        *reinterpret_cast<float4*>(xo) = make_float4(a0, a1, a2, f2h2(xv[0], xv[1]));
        *reinterpret_cast<float4*>(xo + 4) =
            make_float4(f2h2(xv[2], xv[3]), f2h2(xv[4], xv[5]),
                        f2h2(xv[6], xv[7]), f2h2(xv[8], 0.f));
        *reinterpret_cast<float4*>(er + (size_t)n * 4) = make_float4(r0, r1, r2, 0.f);
        return;
    }
    if (b < NB_BIN + NB_EL + NB_PW) {
        // ---- role: W2 -> fp16 effective-transpose table ----
        const int idx = (b - (NB_BIN + NB_EL)) * 256 + t;
        if (idx < 64 * 192) {
            const int n = idx / 192, ke = idx % 192;
            Wt16[idx] = __float2half(W2[(ke & 63) * 192 + (ke >> 6) * 64 + n]);
        }
        return;
    }
    // ---- role: Wa2/Wr2 precompute ----
    if (t < 192) {
        const int h = t >> 6, k = t & 63;
        float sa = 0.f, sr = 0.f;
        for (int f = 0; f < 64; ++f) {
            const float w = W2[k * 192 + h * 64 + f];
            sa += w * al2[h * 64 + f];
            sr += w * ar2[h * 64 + f];
        }
        Wa2[k * 4 + h] = sa;
        Wr2[k * 4 + h] = sr;
        if (h == 0) { Wa2[k * 4 + 3] = 0.f; Wr2[k * 4 + 3] = 0.f; }
    }
}

// ---------------- per bucket scatter (512 threads; bfill totals scan) --------
__global__ void __launch_bounds__(512) k_bscatter2(const unsigned int* __restrict__ stage,
                                                   const int* __restrict__ bfill,
                                                   int* __restrict__ rowp,
                                                   int* __restrict__ col) {
    __shared__ int lcnt[256];
    __shared__ int lpos[256];
    __shared__ int sexc[256];
    __shared__ int sscan[256];
    const int t = threadIdx.x;
    const int b = blockIdx.x;
    const int n0 = b << 8;
    int bv = 0;
    if (t < 256) {
        bv = (t < NBKT) ? bfill[t] : 0;
        sscan[t] = bv;
        lcnt[t] = 0;
    }
    __syncthreads();
    for (int off = 1; off < 256; off <<= 1) {
        int u = 0;
        if (t < 256 && t >= off) u = sscan[t - off];
        __syncthreads();
        if (t < 256) sscan[t] += u;
        __syncthreads();
    }
    const int base = (b == 0) ? 0 : sscan[b - 1];
    const int cnt = bfill[b];
    const unsigned int* __restrict__ st = stage + (size_t)b * BCAP;

    for (int j = t; j < cnt; j += 512)
        atomicAdd(&lcnt[(st[j] >> 16) & 255], 1);
    __syncthreads();
    int v = 0;
    if (t < 256) { v = lcnt[t]; lpos[t] = v; }
    __syncthreads();
    for (int off = 1; off < 256; off <<= 1) {
        int u = 0;
        if (t < 256 && t >= off) u = lpos[t - off];
        __syncthreads();
        if (t < 256) lpos[t] += u;
        __syncthreads();
    }
    if (t < 256) {
        sexc[t] = lpos[t] - v;
        if (n0 + t < N_NODES) rowp[n0 + t] = base + sexc[t];
        lcnt[t] = 0;   // reuse as fill counters
    }
    if (b == NBKT - 1 && t == 0) rowp[N_NODES] = N_EDGES;
    __syncthreads();
    for (int j = t; j < cnt; j += 512) {
        const unsigned int e = st[j];
        const int local = (int)(e >> 16) & 255;
        const int r = atomicAdd(&lcnt[local], 1);
        col[base + sexc[local] + r] = (int)(e & 0xFFFFu);
    }
}

// ---------------- fused L1: agg + gemm2 (2-batch, 32-bit offsets) ------------
__global__ void __launch_bounds__(256, 6) k_l1(const float* __restrict__ xph,
                                               const float* __restrict__ er_in,
                                               const int* __restrict__ rowp,
                                               const int* __restrict__ col,
                                               const float* __restrict__ W1,
                                               const float* __restrict__ b1,
                                               const float* __restrict__ Wa2,
                                               const float* __restrict__ Wr2,
                                               __half* __restrict__ hout,
                                               float* __restrict__ el,
                                               float* __restrict__ er_out) {
    __shared__ union {
        float At[16 * 28];          // agg -> gemm handoff (dead after part compute)
        float vbuf[16][72];         // gemm epilogue staging (aliases At; sync between)
    } u;
    __shared__ float part[3][16][64];
    const int t = threadIdx.x;
    const int wv = t >> 6;
    const int lane = t & 63;
    const int q = lane >> 4;            // node slot within wave
    const int ql = lane & 15;           // lane within quarter
    const int li = wv * 4 + q;          // local node 0..15
    const int nbase = blockIdx.x * 16;  // 3125 * 16 = 50000 exact
    const int n = nbase + li;
    const char* __restrict__ xb = (const char*)xph;

    // ---- aggregation (lane-per-edge, 2-edge batch) ----
    {
        const int jb = rowp[n], je = rowp[n + 1];
        const float4 er4 = *reinterpret_cast<const float4*>(er_in + (size_t)n * 4);
        float acc[27];
#pragma unroll
        for (int j = 0; j < 27; ++j) acc[j] = 0.f;
        float sw0 = 0.f, sw1 = 0.f, sw2 = 0.f;

        for (int e = jb + ql; e < je; e += 32) {
            const int e2 = e + 16;
            const bool v2 = (e2 < je);
            const int off1 = col[e] << 5;
            const int off2 = (v2 ? col[e2] : col[e]) << 5;
            const float4 xa1 = *reinterpret_cast<const float4*>(xb + off1);
            const float4 xb1 = *reinterpret_cast<const float4*>(xb + off1 + 16);
            const float4 xa2 = *reinterpret_cast<const float4*>(xb + off2);
            const float4 xb2 = *reinterpret_cast<const float4*>(xb + off2 + 16);
            const float m2 = v2 ? 1.f : 0.f;
            const float w10 = __expf(lrelu(xa1.x + er4.x));
            const float w11 = __expf(lrelu(xa1.y + er4.y));
            const float w12 = __expf(lrelu(xa1.z + er4.z));
            const float w20 = __expf(lrelu(xa2.x + er4.x)) * m2;
            const float w21 = __expf(lrelu(xa2.y + er4.y)) * m2;
            const float w22 = __expf(lrelu(xa2.z + er4.z)) * m2;
            sw0 += w10 + w20; sw1 += w11 + w21; sw2 += w12 + w22;
            const float2 p10 = h2f(xa1.w), p11 = h2f(xb1.x), p12 = h2f(xb1.y),
                         p13 = h2f(xb1.z), p14 = h2f(xb1.w);
            const float2 p20 = h2f(xa2.w), p21 = h2f(xb2.x), p22 = h2f(xb2.y),
                         p23 = h2f(xb2.z), p24 = h2f(xb2.w);
            const float x1[9] = {p10.x, p10.y, p11.x, p11.y, p12.x, p12.y, p13.x, p13.y, p14.x};
            const float x2[9] = {p20.x, p20.y, p21.x, p21.y, p22.x, p22.y, p23.x, p23.y, p24.x};
#pragma unroll
            for (int k = 0; k < 9; ++k) {
                acc[0 + k]  += w10 * x1[k] + w20 * x2[k];
                acc[9 + k]  += w11 * x1[k] + w21 * x2[k];
                acc[18 + k] += w12 * x1[k] + w22 * x2[k];
            }
        }
#pragma unroll
        for (int off = 1; off < 16; off <<= 1) {
            sw0 += __shfl_xor(sw0, off);
            sw1 += __shfl_xor(sw1, off);
            sw2 += __shfl_xor(sw2, off);
#pragma unroll
            for (int j = 0; j < 27; ++j) acc[j] += __shfl_xor(acc[j], off);
        }
        if (ql == 0) {
            const bool has = (je > jb);
            const float i0 = has ? 1.f / sw0 : 0.f;
            const float i1 = has ? 1.f / sw1 : 0.f;
            const float i2 = has ? 1.f / sw2 : 0.f;
            float* __restrict__ ao = u.At + li * 28;
#pragma unroll
            for (int k = 0; k < 9; ++k) {
                ao[k] = acc[k] * i0;
                ao[9 + k] = acc[9 + k] * i1;
                ao[18 + k] = acc[18 + k] * i2;
            }
        }
    }
    __syncthreads();

    // ---- GEMM (h = wave id, c = lane) ----
    {
        const int h = wv;               // 0..3; h==3 idle for partials
        const int c = lane;
        if (h < 3) {
            float wreg[9];
#pragma unroll
            for (int k = 0; k < 9; ++k) wreg[k] = W1[k * 192 + h * 64 + c];
#pragma unroll
            for (int i = 0; i < 16; ++i) {
                const float* __restrict__ arp = u.At + i * 28 + h * 9;
                float acc = 0.f;
#pragma unroll
                for (int k = 0; k < 9; ++k) acc += arp[k] * wreg[k];
                part[h][i][c] = acc;
            }
        }
        __syncthreads();
        const float bsum = b1[c] + b1[64 + c] + b1[128 + c];
        for (int idx = t; idx < 1024; idx += 256) {
            const int i = idx >> 6, cc = idx & 63;  // cc == c (stride 256)
            const float v = part[0][i][cc] + part[1][i][cc] + part[2][i][cc] + bsum;
            hout[(size_t)(nbase + i) * 64 + cc] = __float2half(v);
            u.vbuf[i][cc] = v;           // aliases At — legal: At dead, sync above
        }
        __syncthreads();
        if (t < 96) {
            const int i = t / 6, r = t % 6;
            const int h3 = (r < 3) ? r : r - 3;
            const float* __restrict__ tab = (r < 3) ? Wa2 : Wr2;
            float s = 0.f;
#pragma unroll 8
            for (int c2 = 0; c2 < 64; ++c2) s += u.vbuf[i][c2] * tab[c2 * 4 + h3];
            if (r < 3) el[(size_t)(nbase + i) * 4 + h3] = s;
            else       er_out[(size_t)(nbase + i) * 4 + h3] = s;
        }
    }
}

// ---------------- L2 aggregation v5: quad-node wave (16 lanes/node) ----------
// Mean degree 16 << old 64-edge chunk: v4 left 75% of lanes idle in the
// el-phase and paid full wave prologue per node. v5: 4 nodes/wave, 16
// lanes/node, each lane owns 4 features (dwordx2/edge, 4 edge-rows per
// wave-instruction, coalesced); no cross-lane acc reduction; x-phase
// unrolled x4 for memory-level parallelism.
__global__ void __launch_bounds__(256, 6) k_aggw64(const __half* __restrict__ x,
                                                   const float* __restrict__ el,
                                                   const float* __restrict__ er,
                                                   const int* __restrict__ rowp,
                                                   const int* __restrict__ col,
                                                   __half* __restrict__ agg) {
    const int t = threadIdx.x;
    const int wv = t >> 6;
    const int lane = t & 63;
    const int q = lane >> 4;            // node slot within wave
    const int ql = lane & 15;           // lane within quarter
    const int n = (blockIdx.x * 4 + wv) * 4 + q;   // grid exact: 3125*16 = 50000
    const int jb = rowp[n], je = rowp[n + 1];

    __shared__ float4 wbuf[4][4][16];   // [wave][quarter][edge] = 4 KB
    const float4 er4 = *reinterpret_cast<const float4*>(er + (size_t)n * 4);
    const char* __restrict__ xbase = (const char*)x;
    const char* __restrict__ elbase = (const char*)el;
    const int foff = ql * 8;            // 4 halfs per lane

    float acc[12];                      // 4 feats x 3 heads
#pragma unroll
    for (int j = 0; j < 12; ++j) acc[j] = 0.f;
    float sw0 = 0.f, sw1 = 0.f, sw2 = 0.f;

    for (int c0 = jb; c0 < je; c0 += 16) {
        const int cnt = min(16, je - c0);
        if (ql < cnt) {
            const int s = col[c0 + ql];
            const float4 e4 = *reinterpret_cast<const float4*>(elbase + (s << 4));
            const float w0 = __expf(lrelu(e4.x + er4.x));
            const float w1 = __expf(lrelu(e4.y + er4.y));
            const float w2 = __expf(lrelu(e4.z + er4.z));
            wbuf[wv][q][ql] = make_float4(w0, w1, w2, __int_as_float(s << 7));
            sw0 += w0; sw1 += w1; sw2 += w2;
        }
        __builtin_amdgcn_wave_barrier();
        int k = 0;
        for (; k + 4 <= cnt; k += 4) {
            const float4 q0 = wbuf[wv][q][k];
            const float4 q1 = wbuf[wv][q][k + 1];
            const float4 q2 = wbuf[wv][q][k + 2];
            const float4 q3 = wbuf[wv][q][k + 3];
            const float2 r0 = *reinterpret_cast<const float2*>(xbase + (__float_as_int(q0.w) + foff));
            const float2 r1 = *reinterpret_cast<const float2*>(xbase + (__float_as_int(q1.w) + foff));
            const float2 r2 = *reinterpret_cast<const float2*>(xbase + (__float_as_int(q2.w) + foff));
            const float2 r3 = *reinterpret_cast<const float2*>(xbase + (__float_as_int(q3.w) + foff));
            const float2 a01 = h2f(r0.x), a23 = h2f(r0.y);
            const float2 b01 = h2f(r1.x), b23 = h2f(r1.y);
            const float2 c01 = h2f(r2.x), c23 = h2f(r2.y);
            const float2 d01 = h2f(r3.x), d23 = h2f(r3.y);
            acc[0] += q0.x * a01.x + q1.x * b01.x + q2.x * c01.x + q3.x * d01.x;
            acc[1] += q0.x * a01.y + q1.x * b01.y + q2.x * c01.y + q3.x * d01.y;
            acc[2] += q0.x * a23.x + q1.x * b23.x + q2.x * c23.x + q3.x * d23.x;
            acc[3] += q0.x * a23.y + q1.x * b23.y + q2.x * c23.y + q3.x * d23.y;
            acc[4] += q0.y * a01.x + q1.y * b01.x + q2.y * c01.x + q3.y * d01.x;
            acc[5] += q0.y * a01.y + q1.y * b01.y + q2.y * c01.y + q3.y * d01.y;
            acc[6] += q0.y * a23.x + q1.y * b23.x + q2.y * c23.x + q3.y * d23.x;
            acc[7] += q0.y * a23.y + q1.y * b23.y + q2.y * c23.y + q3.y * d23.y;
            acc[8]  += q0.z * a01.x + q1.z * b01.x + q2.z * c01.x + q3.z * d01.x;
            acc[9]  += q0.z * a01.y + q1.z * b01.y + q2.z * c01.y + q3.z * d01.y;
            acc[10] += q0.z * a23.x + q1.z * b23.x + q2.z * c23.x + q3.z * d23.x;
            acc[11] += q0.z * a23.y + q1.z * b23.y + q2.z * c23.y + q3.z * d23.y;
        }
        for (; k < cnt; ++k) {
            const float4 q0 = wbuf[wv][q][k];
            const float2 r0 = *reinterpret_cast<const float2*>(xbase + (__float_as_int(q0.w) + foff));
            const float2 a01 = h2f(r0.x), a23 = h2f(r0.y);
            acc[0] += q0.x * a01.x; acc[1] += q0.x * a01.y;
            acc[2] += q0.x * a23.x; acc[3] += q0.x * a23.y;
            acc[4] += q0.y * a01.x; acc[5] += q0.y * a01.y;
            acc[6] += q0.y * a23.x; acc[7] += q0.y * a23.y;
            acc[8]  += q0.z * a01.x; acc[9]  += q0.z * a01.y;
            acc[10] += q0.z * a23.x; acc[11] += q0.z * a23.y;
        }
    }
    // sw reduction within the 16-lane quarter (masks <16 stay in-quarter)
#pragma unroll
    for (int off = 1; off < 16; off <<= 1) {
        sw0 += __shfl_xor(sw0, off);
        sw1 += __shfl_xor(sw1, off);
        sw2 += __shfl_xor(sw2, off);
    }
    // output: lane ql writes feats 4ql..4ql+3 for each head (dwordx2 each)
    {
        __half* __restrict__ ao = agg + (size_t)n * 192 + ql * 4;
        if (je > jb) {
            const float i0 = 1.f / sw0, i1 = 1.f / sw1, i2 = 1.f / sw2;
            *reinterpret_cast<float2*>(ao) =
                make_float2(f2h2(acc[0] * i0, acc[1] * i0), f2h2(acc[2] * i0, acc[3] * i0));
            *reinterpret_cast<float2*>(ao + 64) =
                make_float2(f2h2(acc[4] * i1, acc[5] * i1), f2h2(acc[6] * i1, acc[7] * i1));
            *reinterpret_cast<float2*>(ao + 128) =
                make_float2(f2h2(acc[8] * i2, acc[9] * i2), f2h2(acc[10] * i2, acc[11] * i2));
        } else {
            const float2 z = make_float2(f2h2(0.f, 0.f), f2h2(0.f, 0.f));
            *reinterpret_cast<float2*>(ao) = z;
            *reinterpret_cast<float2*>(ao + 64) = z;
            *reinterpret_cast<float2*>(ao + 128) = z;
        }
    }
}

// ---------------- fused L2 GEMM (MFMA) + layer-3 features (LDS handoff) ------
__global__ void __launch_bounds__(256) k_l23(const __half* __restrict__ aggH,
                                             const __half* __restrict__ Wt,
                                             const float* __restrict__ b2,
                                             const float* __restrict__ W3,
                                             const float* __restrict__ al3,
                                             const float* __restrict__ ar3,
                                             float* __restrict__ feat3p,
                                             float* __restrict__ er3) {
    __shared__ float xl[64 * 68];
    __shared__ float Wl[64 * 6];
    __shared__ float Wal[64 * 3];
    __shared__ float Wrl[64 * 3];
    const int t = threadIdx.x;
    const int n0 = blockIdx.x * 64;             // 782 blocks; last has nvalid=16
    const int nvalid = min(64, N_NODES - n0);

    {
        const int wv = t >> 6;
        const int lane = t & 63;
        const int quad = lane >> 4;
        const int t16 = lane & 15;
        const int nwave = n0 + wv * 16;
        const int arow = min(nwave + t16, N_NODES - 1);
        half8 a[6];
#pragma unroll
        for (int kb = 0; kb < 6; ++kb)
            a[kb] = *reinterpret_cast<const half8*>(aggH + (size_t)arow * 192 + kb * 32 + quad * 8);
#pragma unroll
        for (int nt = 0; nt < 4; ++nt) {
            const int c = nt * 16 + t16;
            const float bs = b2[c] + b2[64 + c] + b2[128 + c];
            const __half* __restrict__ bt = Wt + (size_t)c * 192 + quad * 8;
            f32x4 acc = {0.f, 0.f, 0.f, 0.f};
#pragma unroll
            for (int kb = 0; kb < 6; ++kb) {
                const half8 bfr = *reinterpret_cast<const half8*>(bt + kb * 32);
                acc = __builtin_amdgcn_mfma_f32_16x16x32_f16(a[kb], bfr, acc, 0, 0, 0);
            }
#pragma unroll
            for (int r = 0; r < 4; ++r)
                xl[(wv * 16 + quad * 4 + r) * 68 + c] = acc[r] + bs;
        }
    }
    for (int idx = t; idx < 384; idx += 256) Wl[idx] = W3[idx];
    if (t < 192) {
        const int k = t & 63, h = t >> 6;
        Wal[k * 3 + h] = W3[k * 6 + h * 2] * al3[h * 2] + W3[k * 6 + h * 2 + 1] * al3[h * 2 + 1];
        Wrl[k * 3 + h] = W3[k * 6 + h * 2] * ar3[h * 2] + W3[k * 6 + h * 2 + 1] * ar3[h * 2 + 1];
    }
    __syncthreads();

#pragma unroll
    for (int hp = 0; hp < 2; ++hp) {
        const int i = (t >> 3) + hp * 32;
        const int slot = t & 7;
        if (i < nvalid && slot < 6) {
            float acc = 0.f;
#pragma unroll
            for (int k4 = 0; k4 < 16; ++k4) {
                const float4 xv = *reinterpret_cast<const float4*>(&xl[i * 68 + 4 * k4]);
                acc += Wl[(4 * k4 + 0) * 6 + slot] * xv.x;
                acc += Wl[(4 * k4 + 1) * 6 + slot] * xv.y;
                acc += Wl[(4 * k4 + 2) * 6 + slot] * xv.z;
                acc += Wl[(4 * k4 + 3) * 6 + slot] * xv.w;
            }
            reinterpret_cast<__half*>(feat3p + (size_t)(n0 + i) * 8)[6 + slot] = __float2half(acc);
        }
        if (t < 192) {
            const int ii = t / 6 + hp * 32, ss = t % 6;
            if (ii < nvalid) {
                const int hh = (ss < 3) ? ss : ss - 3;
                const float* __restrict__ wt = (ss < 3) ? Wal : Wrl;
                float acc = 0.f;
#pragma unroll 4
                for (int k = 0; k < 64; ++k) acc += xl[ii * 68 + k] * wt[k * 3 + hh];
                if (ss < 3) feat3p[(size_t)(n0 + ii) * 8 + hh] = acc;   // el3 f32 at 0..2
                else        er3[(size_t)(n0 + ii) * 4 + hh] = acc;
            }
        }
    }
}

// ---------------- layer-3 aggregation: 4-edge batch, 32-bit offsets ----------
__global__ void __launch_bounds__(256, 4) k_agg3(const float* __restrict__ feat3p,
                                                 const float* __restrict__ er3,
                                                 const float* __restrict__ b3,
                                                 const int* __restrict__ rowp,
                                                 const int* __restrict__ col,
                                                 float* __restrict__ out) {
    const int tid = threadIdx.x;
    const int wv = tid >> 6;
    const int lane = tid & 63;
    const int q = lane >> 4;
    const int ql = lane & 15;
    const int n = (blockIdx.x * 4 + wv) * 4 + q;   // grid exact: 3125*16 = 50000
    const int jb = rowp[n], je = rowp[n + 1];
    const float4 er4 = *reinterpret_cast<const float4*>(er3 + (size_t)n * 4);
    const char* __restrict__ fb = (const char*)feat3p;

    float acc[6];
#pragma unroll
    for (int j = 0; j < 6; ++j) acc[j] = 0.f;
    float sw0 = 0.f, sw1 = 0.f, sw2 = 0.f;

    for (int e = jb + ql; e < je; e += 64) {
        const int eb = e + 16, ec = e + 32, ed = e + 48;
        const bool vb = (eb < je), vc = (ec < je), vd = (ed < je);
        const int sa = col[e];
        const int offa = sa << 5;
        const int offb = (vb ? col[eb] : sa) << 5;
        const int offc = (vc ? col[ec] : sa) << 5;
        const int offd = (vd ? col[ed] : sa) << 5;
        const float4 fa1 = *reinterpret_cast<const float4*>(fb + offa);
        const float2 fb1 = *reinterpret_cast<const float2*>(fb + offa + 16);
        const float4 fa2 = *reinterpret_cast<const float4*>(fb + offb);
        const float2 fb2 = *reinterpret_cast<const float2*>(fb + offb + 16);
        const float4 fa3 = *reinterpret_cast<const float4*>(fb + offc);
        const float2 fb3 = *reinterpret_cast<const float2*>(fb + offc + 16);
        const float4 fa4 = *reinterpret_cast<const float4*>(fb + offd);
        const float2 fb4 = *reinterpret_cast<const float2*>(fb + offd + 16);
        const float mb = vb ? 1.f : 0.f, mc = vc ? 1.f : 0.f, md = vd ? 1.f : 0.f;
        const float w10 = __expf(lrelu(fa1.x + er4.x));
        const float w11 = __expf(lrelu(fa1.y + er4.y));
        const float w12 = __expf(lrelu(fa1.z + er4.z));
        const float w20 = __expf(lrelu(fa2.x + er4.x)) * mb;
        const float w21 = __expf(lrelu(fa2.y + er4.y)) * mb;
        const float w22 = __expf(lrelu(fa2.z + er4.z)) * mb;
        const float w30 = __expf(lrelu(fa3.x + er4.x)) * mc;
        const float w31 = __expf(lrelu(fa3.y + er4.y)) * mc;
        const float w32 = __expf(lrelu(fa3.z + er4.z)) * mc;
        const float w40 = __expf(lrelu(fa4.x + er4.x)) * md;
        const float w41 = __expf(lrelu(fa4.y + er4.y)) * md;
        const float w42 = __expf(lrelu(fa4.z + er4.z)) * md;
        sw0 += (w10 + w20) + (w30 + w40);
        sw1 += (w11 + w21) + (w31 + w41);
        sw2 += (w12 + w22) + (w32 + w42);
        const float2 f01a = h2f(fa1.w), f23a = h2f(fb1.x), f45a = h2f(fb1.y);
        const float2 f01b = h2f(fa2.w), f23b = h2f(fb2.x), f45b = h2f(fb2.y);
        const float2 f01c = h2f(fa3.w), f23c = h2f(fb3.x), f45c = h2f(fb3.y);
        const float2 f01d = h2f(fa4.w), f23d = h2f(fb4.x), f45d = h2f(fb4.y);
        acc[0] += (w10 * f01a.x + w20 * f01b.x) + (w30 * f01c.x + w40 * f01d.x);
        acc[1] += (w10 * f01a.y + w20 * f01b.y) + (w30 * f01c.y + w40 * f01d.y);
        acc[2] += (w11 * f23a.x + w21 * f23b.x) + (w31 * f23c.x + w41 * f23d.x);
        acc[3] += (w11 * f23a.y + w21 * f23b.y) + (w31 * f23c.y + w41 * f23d.y);
        acc[4] += (w12 * f45a.x + w22 * f45b.x) + (w32 * f45c.x + w42 * f45d.x);
        acc[5] += (w12 * f45a.y + w22 * f45b.y) + (w32 * f45c.y + w42 * f45d.y);
    }
#pragma unroll
    for (int off = 1; off < 16; off <<= 1) {
        sw0 += __shfl_xor(sw0, off);
        sw1 += __shfl_xor(sw1, off);
        sw2 += __shfl_xor(sw2, off);
#pragma unroll
        for (int j = 0; j < 6; ++j) acc[j] += __shfl_xor(acc[j], off);
    }
    if (ql == 0) {
        const bool has = (je > jb);
        const float i0 = has ? 1.f / sw0 : 0.f;
        const float i1 = has ? 1.f / sw1 : 0.f;
        const float i2 = has ? 1.f / sw2 : 0.f;
        const float o0 = acc[0] * i0 + acc[2] * i1 + acc[4] * i2 + b3[0] + b3[2] + b3[4];
        const float o1 = acc[1] * i0 + acc[3] * i1 + acc[5] * i2 + b3[1] + b3[3] + b3[5];
        *reinterpret_cast<float2*>(out + (size_t)n * 2) = make_float2(o0, o1);
    }
}

extern "C" void kernel_launch(void* const* d_in, const int* in_sizes, int n_in,
                              void* d_out, int out_size, void* d_ws, size_t ws_size,
                              hipStream_t stream) {
    const float* feats = (const float*)d_in[0];
    const int* src = (const int*)d_in[1];
    const int* dst = (const int*)d_in[2];
    const float* W1 = (const float*)d_in[3];
    const float* al1 = (const float*)d_in[4];
    const float* ar1 = (const float*)d_in[5];
    const float* b1 = (const float*)d_in[6];
    const float* W2 = (const float*)d_in[7];
    const float* al2 = (const float*)d_in[8];
    const float* ar2 = (const float*)d_in[9];
    const float* b2 = (const float*)d_in[10];
    const float* W3 = (const float*)d_in[11];
    const float* al3 = (const float*)d_in[12];
    const float* ar3 = (const float*)d_in[13];
    const float* b3 = (const float*)d_in[14];
    float* out = (float*)d_out;

    char* ws = (char*)d_ws;
    size_t off = 0;
    auto alloc = [&](size_t bytes) {
        void* p = ws + off;
        off += (bytes + 255) & ~(size_t)255;
        return p;
    };
    __half* aggH = (__half*)alloc((size_t)N_NODES * 192 * 2);    // L2 agg fp16 [N][192]
    __half* hbufH = (__half*)alloc((size_t)N_NODES * 64 * 2);    // fp16 L1 hidden
    float* xph = (float*)alloc((size_t)N_NODES * 8 * 4);         // packed el1(f32)+x(f16)
    float* el = (float*)alloc((size_t)N_NODES * 4 * 4);
    float* er = (float*)alloc((size_t)N_NODES * 4 * 4);
    int* bfill = (int*)alloc(256 * 4);
    int* rowp = (int*)alloc((size_t)(N_NODES + 1) * 4);
    int* col = (int*)alloc((size_t)N_EDGES * 4);
    unsigned int* stage = (unsigned int*)alloc((size_t)NBKT * BCAP * 4);  // 3.5 MB
    __half* Wt16 = (__half*)alloc((size_t)64 * 192 * 2);         // 24 KB fp16 W2^T
    float* Wa2 = (float*)alloc(256 * 4);
    float* Wr2 = (float*)alloc(256 * 4);
    float* feat3p = (float*)alloc((size_t)N_NODES * 8 * 4);      // packed el3(f32)+feat(f16)
    (void)ws_size;

    const int qb = N_NODES / 16;            // 16 nodes/block kernels
    const int lb = (N_NODES + 63) / 64;     // k_l23: 64 nodes/block

    // ---- CSR build + front prep (single edge sweep via fixed-cap buckets) ----
    hipMemsetAsync(bfill, 0, 256 * 4, stream);
    k_front<<<NB_BIN + NB_EL + NB_PW + 1, 256, 0, stream>>>(
        src, dst, bfill, stage, feats, W1, al1, ar1, xph, er, W2, Wt16,
        al2, ar2, Wa2, Wr2);
    k_bscatter2<<<NBKT, 512, 0, stream>>>(stage, bfill, rowp, col);

    // ---- layer 1 (agg + GEMM fused) ----
    k_l1<<<qb, 256, 0, stream>>>(xph, er, rowp, col, W1, b1, Wa2, Wr2, hbufH, el, er);

    // ---- layer 2 aggregation (quad-node waves) ----
    k_aggw64<<<qb, 256, 0, stream>>>(hbufH, el, er, rowp, col, aggH);

    // ---- layer-2 GEMM + layer-3 features (fused) ----
    k_l23<<<lb, 256, 0, stream>>>(aggH, Wt16, b2, W3, al3, ar3, feat3p, er);

    // ---- layer 3 aggregation ----
    k_agg3<<<qb, 256, 0, stream>>>(feat3p, er, b3, rowp, col, out);
}